// Round 1
// baseline (770.102 us; speedup 1.0000x reference)
//
#include <hip/hip_runtime.h>
#include <hip/hip_bf16.h>

// Problem constants (match reference)
#define NN   40000
#define EE   640000
#define INF_ 128
#define HIDF 128
#define H2F  64
#define DECF 64
#define TT   2

// ---------------- CSR build ----------------

__global__ __launch_bounds__(256) void hist_k(const int* __restrict__ dst, int E, int* __restrict__ cnt) {
    int i = blockIdx.x * 256 + threadIdx.x;
    if (i < E) atomicAdd(&cnt[dst[i]], 1);
}

__global__ __launch_bounds__(256) void scan1_k(const int* __restrict__ cnt, int n,
                                               int* __restrict__ offs, int* __restrict__ bsum) {
    __shared__ int tmp[256];
    int i = blockIdx.x * 256 + threadIdx.x;
    int v = (i < n) ? cnt[i] : 0;
    tmp[threadIdx.x] = v;
    __syncthreads();
    for (int d = 1; d < 256; d <<= 1) {
        int t = (threadIdx.x >= d) ? tmp[threadIdx.x - d] : 0;
        __syncthreads();
        tmp[threadIdx.x] += t;
        __syncthreads();
    }
    if (i < n) offs[i] = tmp[threadIdx.x] - v;   // exclusive
    if (threadIdx.x == 255) bsum[blockIdx.x] = tmp[255];
}

__global__ void scan2_k(int* bsum, int nb) {
    if (threadIdx.x == 0 && blockIdx.x == 0) {
        int acc = 0;
        for (int b = 0; b < nb; b++) { int t = bsum[b]; bsum[b] = acc; acc += t; }
    }
}

__global__ __launch_bounds__(256) void scan3_k(int* __restrict__ offs, int n,
                                               const int* __restrict__ bsum, int E) {
    int i = blockIdx.x * 256 + threadIdx.x;
    if (i < n) offs[i] += bsum[blockIdx.x];
    if (i == 0) offs[n] = E;
}

__global__ __launch_bounds__(256) void scatter_k(const int* __restrict__ src, const int* __restrict__ dst,
                                                 int E, const int* __restrict__ offs,
                                                 int* __restrict__ cursor, int* __restrict__ ssrc) {
    int i = blockIdx.x * 256 + threadIdx.x;
    if (i < E) {
        int d = dst[i];
        int p = offs[d] + atomicAdd(&cursor[d], 1);
        ssrc[p] = src[i];
    }
}

// ---------------- decision MLP (128 -> 64 relu -> 2 softmax) ----------------

__global__ __launch_bounds__(256) void dec_k(const float* __restrict__ X,
                                             const float* __restrict__ dw1, const float* __restrict__ db1,
                                             const float* __restrict__ dw2, const float* __restrict__ db2,
                                             float* __restrict__ wdec, int N) {
    __shared__ float xs[4][128];
    __shared__ float hid[4][64];
    __shared__ float lg[4][2];
    int n0 = blockIdx.x * 4;
    int sub = threadIdx.x >> 6, u = threadIdx.x & 63;
    for (int idx = threadIdx.x; idx < 4 * 128; idx += 256) {
        int r = idx >> 7, k = idx & 127;
        int n = n0 + r;
        xs[r][k] = (n < N) ? X[n * 128 + k] : 0.f;
    }
    __syncthreads();
    float a = db1[u];
    #pragma unroll 4
    for (int k = 0; k < 128; k++) a += xs[sub][k] * dw1[k * 64 + u];
    hid[sub][u] = fmaxf(a, 0.f);
    __syncthreads();
    if (u < 2) {
        float l = db2[u];
        #pragma unroll 4
        for (int j = 0; j < 64; j++) l += hid[sub][j] * dw2[j * 2 + u];
        lg[sub][u] = l;
    }
    __syncthreads();
    if (u == 0) {
        int n = n0 + sub;
        if (n < N) {
            float l0 = lg[sub][0], l1 = lg[sub][1];
            float mm = fmaxf(l0, l1);
            float e0 = __expf(l0 - mm), e1 = __expf(l1 - mm);
            float s = e0 + e1;
            wdec[n * 2 + 0] = e0 / s;
            wdec[n * 2 + 1] = e1 / s;
        }
    }
}

// ---------------- GEMM: H[N,M] = X[N,128] @ W[128,M] ----------------

template <int M>
__global__ __launch_bounds__(256) void gemm_k(const float* __restrict__ X, const float* __restrict__ W,
                                              float* __restrict__ H, int N) {
    constexpr int K = 128;
    constexpr int NB = 16;
    constexpr int G = 256 / M;   // row groups
    constexpr int R = NB / G;    // rows per thread
    __shared__ float xs[NB][K + 1];
    int n0 = blockIdx.x * NB;
    for (int idx = threadIdx.x; idx < NB * K; idx += 256) {
        int r = idx >> 7, k = idx & 127;
        xs[r][k] = X[(n0 + r) * K + k];
    }
    __syncthreads();
    const int c = threadIdx.x % M;
    const int g = threadIdx.x / M;
    float acc[R];
    #pragma unroll
    for (int r = 0; r < R; r++) acc[r] = 0.f;
    #pragma unroll 4
    for (int k = 0; k < K; k++) {
        float wv = W[k * M + c];
        #pragma unroll
        for (int r = 0; r < R; r++) acc[r] += xs[g * R + r][k] * wv;
    }
    #pragma unroll
    for (int r = 0; r < R; r++) H[(n0 + g * R + r) * M + c] = acc[r];
}

// ---------------- attention scalars: el = H@a0, er = H@a1 ----------------

template <int F>
__global__ __launch_bounds__(64) void attsc_k(const float* __restrict__ H,
                                              const float* __restrict__ a0, const float* __restrict__ a1,
                                              float* __restrict__ el, float* __restrict__ er, int N) {
    int n = blockIdx.x;
    int t = threadIdx.x;
    float sl = 0.f, sr = 0.f;
    #pragma unroll
    for (int c = t; c < F; c += 64) {
        float h = H[n * F + c];
        sl += h * a0[c];
        sr += h * a1[c];
    }
    #pragma unroll
    for (int off = 32; off > 0; off >>= 1) {
        sl += __shfl_down(sl, off);
        sr += __shfl_down(sr, off);
    }
    if (t == 0) { el[n] = sl; er[n] = sr; }
}

// ---------------- per-node GAT aggregation (CSR, no atomics) ----------------

template <int F, bool FIRST>
__global__ __launch_bounds__(F) void gat_k(const int* __restrict__ offs, const int* __restrict__ ssrc,
                                           const float* __restrict__ el, const float* __restrict__ er,
                                           const float* __restrict__ H, const float* __restrict__ wdec,
                                           int tsel, float* __restrict__ out, int N) {
    constexpr int MAXDEG = 512;
    __shared__ int   sj[MAXDEG];
    __shared__ float ej[MAXDEG];
    __shared__ float red[F];
    int n = blockIdx.x;
    int beg = offs[n];
    int deg = offs[n + 1] - beg;
    if (deg > MAXDEG) deg = MAXDEG;   // statistically impossible (Poisson mean 16)
    int tid = threadIdx.x;
    float ern = er[n];
    for (int j = tid; j < deg; j += F) {
        int s = ssrc[beg + j];
        sj[j] = s;
        float e = el[s] + ern;
        ej[j] = (e > 0.f) ? e : 0.2f * e;
    }
    __syncthreads();
    // segment max
    float m = -1e30f;
    for (int j = tid; j < deg; j += F) m = fmaxf(m, ej[j]);
    red[tid] = m;
    __syncthreads();
    #pragma unroll
    for (int s = F / 2; s > 0; s >>= 1) {
        if (tid < s) red[tid] = fmaxf(red[tid], red[tid + s]);
        __syncthreads();
    }
    m = red[0];
    __syncthreads();
    // exp + segment sum
    float ssum = 0.f;
    for (int j = tid; j < deg; j += F) {
        float ex = __expf(ej[j] - m);
        ej[j] = ex;
        ssum += ex;
    }
    red[tid] = ssum;
    __syncthreads();
    #pragma unroll
    for (int s = F / 2; s > 0; s >>= 1) {
        if (tid < s) red[tid] += red[tid + s];
        __syncthreads();
    }
    float coef = wdec[n * 2 + tsel] / (red[0] + 1e-9f);
    // weighted gather-accumulate: feature `tid`
    float acc = 0.f;
    for (int j = 0; j < deg; j++) acc += ej[j] * H[sj[j] * F + tid];
    acc *= coef;
    if (FIRST) {
        out[n * F + tid] = acc;
    } else {
        float v = out[n * F + tid] + acc;
        out[n * F + tid] = fmaxf(v, 0.f);
    }
}

// ---------------- head: 64 -> 32 relu -> 2 softmax ----------------

__global__ __launch_bounds__(256) void head_k(const float* __restrict__ H2,
                                              const float* __restrict__ fc1w, const float* __restrict__ fc1b,
                                              const float* __restrict__ fc2w, const float* __restrict__ fc2b,
                                              float* __restrict__ out, int N) {
    __shared__ float xs[4][64];
    __shared__ float hid[4][32];
    int n0 = blockIdx.x * 4;
    int sub = threadIdx.x >> 6, u = threadIdx.x & 63;
    for (int idx = threadIdx.x; idx < 4 * 64; idx += 256) {
        int r = idx >> 6, k = idx & 63;
        int n = n0 + r;
        xs[r][k] = (n < N) ? H2[n * 64 + k] : 0.f;
    }
    __syncthreads();
    if (u < 32) {
        float a = fc1b[u];
        #pragma unroll 4
        for (int k = 0; k < 64; k++) a += xs[sub][k] * fc1w[k * 32 + u];
        hid[sub][u] = fmaxf(a, 0.f);
    }
    __syncthreads();
    if (u == 0) {
        int n = n0 + sub;
        if (n < N) {
            float l0 = fc2b[0], l1 = fc2b[1];
            #pragma unroll 4
            for (int j = 0; j < 32; j++) {
                float h = hid[sub][j];
                l0 += h * fc2w[j * 2 + 0];
                l1 += h * fc2w[j * 2 + 1];
            }
            float mm = fmaxf(l0, l1);
            float e0 = __expf(l0 - mm), e1 = __expf(l1 - mm);
            float s = e0 + e1;
            out[n * 2 + 0] = e0 / s;
            out[n * 2 + 1] = e1 / s;
        }
    }
}

// ---------------- launch ----------------

extern "C" void kernel_launch(void* const* d_in, const int* in_sizes, int n_in,
                              void* d_out, int out_size, void* d_ws, size_t ws_size,
                              hipStream_t stream) {
    const float* x     = (const float*)d_in[0];
    const int*   eiA   = (const int*)d_in[1];
    const int*   eiB   = (const int*)d_in[2];
    const float* W1    = (const float*)d_in[3];
    const float* a1    = (const float*)d_in[4];
    const float* d1w1  = (const float*)d_in[5];
    const float* d1b1  = (const float*)d_in[6];
    const float* d1w2  = (const float*)d_in[7];
    const float* d1b2  = (const float*)d_in[8];
    const float* W2    = (const float*)d_in[9];
    const float* a2    = (const float*)d_in[10];
    const float* d2w1  = (const float*)d_in[11];
    const float* d2b1  = (const float*)d_in[12];
    const float* d2w2  = (const float*)d_in[13];
    const float* d2b2  = (const float*)d_in[14];
    const float* fc1w  = (const float*)d_in[15];
    const float* fc1b  = (const float*)d_in[16];
    const float* fc2w  = (const float*)d_in[17];
    const float* fc2b  = (const float*)d_in[18];
    float* out = (float*)d_out;

    const int N = NN, E = EE;

    // workspace carve-up (256B aligned)
    char* ws = (char*)d_ws;
    size_t off = 0;
    auto alloc = [&](size_t bytes) -> char* {
        char* p = ws + off;
        off = (off + bytes + 255) & ~(size_t)255;
        return p;
    };
    int*   offs0 = (int*)alloc((N + 1) * sizeof(int));
    int*   offs1 = (int*)alloc((N + 1) * sizeof(int));
    int*   cnt0  = (int*)alloc(N * sizeof(int));
    int*   cnt1  = (int*)alloc(N * sizeof(int));
    int*   ssrc0 = (int*)alloc(E * sizeof(int));
    int*   ssrc1 = (int*)alloc(E * sizeof(int));
    int*   bsum  = (int*)alloc(1024 * sizeof(int));
    float* wdec  = (float*)alloc(N * 2 * sizeof(float));
    float* el0   = (float*)alloc(N * sizeof(float));
    float* er0   = (float*)alloc(N * sizeof(float));
    float* el1   = (float*)alloc(N * sizeof(float));
    float* er1   = (float*)alloc(N * sizeof(float));
    float* hA    = (float*)alloc((size_t)N * 128 * sizeof(float));
    float* hB    = (float*)alloc((size_t)N * 128 * sizeof(float));
    float* hOut1 = (float*)alloc((size_t)N * 128 * sizeof(float));
    float* hOut2 = (float*)alloc((size_t)N * 64 * sizeof(float));

    const int nScanBlocks = (N + 255) / 256;
    const int nEdgeBlocks = (E + 255) / 256;

    // ---- CSR build, type A ----
    hipMemsetAsync(cnt0, 0, N * sizeof(int), stream);
    hist_k<<<nEdgeBlocks, 256, 0, stream>>>(eiA + E, E, cnt0);
    scan1_k<<<nScanBlocks, 256, 0, stream>>>(cnt0, N, offs0, bsum);
    scan2_k<<<1, 64, 0, stream>>>(bsum, nScanBlocks);
    scan3_k<<<nScanBlocks, 256, 0, stream>>>(offs0, N, bsum, E);
    hipMemsetAsync(cnt0, 0, N * sizeof(int), stream);
    scatter_k<<<nEdgeBlocks, 256, 0, stream>>>(eiA, eiA + E, E, offs0, cnt0, ssrc0);

    // ---- CSR build, type B ----
    hipMemsetAsync(cnt1, 0, N * sizeof(int), stream);
    hist_k<<<nEdgeBlocks, 256, 0, stream>>>(eiB + E, E, cnt1);
    scan1_k<<<nScanBlocks, 256, 0, stream>>>(cnt1, N, offs1, bsum);
    scan2_k<<<1, 64, 0, stream>>>(bsum, nScanBlocks);
    scan3_k<<<nScanBlocks, 256, 0, stream>>>(offs1, N, bsum, E);
    hipMemsetAsync(cnt1, 0, N * sizeof(int), stream);
    scatter_k<<<nEdgeBlocks, 256, 0, stream>>>(eiB, eiB + E, E, offs1, cnt1, ssrc1);

    // ---- Layer 1 ----
    dec_k<<<N / 4, 256, 0, stream>>>(x, d1w1, d1b1, d1w2, d1b2, wdec, N);
    gemm_k<128><<<N / 16, 256, 0, stream>>>(x, W1, hA, N);
    gemm_k<128><<<N / 16, 256, 0, stream>>>(x, W1 + 128 * 128, hB, N);
    attsc_k<128><<<N, 64, 0, stream>>>(hA, a1, a1 + 128, el0, er0, N);
    attsc_k<128><<<N, 64, 0, stream>>>(hB, a1 + 2 * 128, a1 + 3 * 128, el1, er1, N);
    gat_k<128, true><<<N, 128, 0, stream>>>(offs0, ssrc0, el0, er0, hA, wdec, 0, hOut1, N);
    gat_k<128, false><<<N, 128, 0, stream>>>(offs1, ssrc1, el1, er1, hB, wdec, 1, hOut1, N);

    // ---- Layer 2 ----
    dec_k<<<N / 4, 256, 0, stream>>>(hOut1, d2w1, d2b1, d2w2, d2b2, wdec, N);
    gemm_k<64><<<N / 16, 256, 0, stream>>>(hOut1, W2, hA, N);
    gemm_k<64><<<N / 16, 256, 0, stream>>>(hOut1, W2 + 128 * 64, hB, N);
    attsc_k<64><<<N, 64, 0, stream>>>(hA, a2, a2 + 64, el0, er0, N);
    attsc_k<64><<<N, 64, 0, stream>>>(hB, a2 + 2 * 64, a2 + 3 * 64, el1, er1, N);
    gat_k<64, true><<<N, 64, 0, stream>>>(offs0, ssrc0, el0, er0, hA, wdec, 0, hOut2, N);
    gat_k<64, false><<<N, 64, 0, stream>>>(offs1, ssrc1, el1, er1, hB, wdec, 1, hOut2, N);

    // ---- head ----
    head_k<<<N / 4, 256, 0, stream>>>(hOut2, fc1w, fc1b, fc2w, fc2b, out, N);
}

// Round 2
// 723.660 us; speedup vs baseline: 1.0642x; 1.0642x over previous
//
#include <hip/hip_runtime.h>
#include <hip/hip_bf16.h>

#define NN   40000
#define EE   640000
#define MAXDEG 512

// ---------------- CSR build (both edge types concatenated: cnt[2N], offs[2N+1], ssrc[2E]) ----------------

__global__ __launch_bounds__(256) void hist2_k(const int* __restrict__ dstA, const int* __restrict__ dstB,
                                               int E, int* __restrict__ cnt, int N) {
    int i = blockIdx.x * 256 + threadIdx.x;
    if (i < E)            atomicAdd(&cnt[dstA[i]], 1);
    else if (i < 2 * E)   atomicAdd(&cnt[N + dstB[i - E]], 1);
}

__global__ __launch_bounds__(256) void scan1_k(const int* __restrict__ cnt, int n,
                                               int* __restrict__ offs, int* __restrict__ bsum) {
    __shared__ int tmp[256];
    int i = blockIdx.x * 256 + threadIdx.x;
    int v = (i < n) ? cnt[i] : 0;
    tmp[threadIdx.x] = v;
    __syncthreads();
    for (int d = 1; d < 256; d <<= 1) {
        int t = (threadIdx.x >= d) ? tmp[threadIdx.x - d] : 0;
        __syncthreads();
        tmp[threadIdx.x] += t;
        __syncthreads();
    }
    if (i < n) offs[i] = tmp[threadIdx.x] - v;   // exclusive
    if (threadIdx.x == 255) bsum[blockIdx.x] = tmp[255];
}

__global__ __launch_bounds__(512) void scan2_k(int* __restrict__ bsum, int nb) {
    __shared__ int tmp[512];
    int t = threadIdx.x;
    int v = (t < nb) ? bsum[t] : 0;
    tmp[t] = v;
    __syncthreads();
    for (int d = 1; d < 512; d <<= 1) {
        int x = (t >= d) ? tmp[t - d] : 0;
        __syncthreads();
        tmp[t] += x;
        __syncthreads();
    }
    if (t < nb) bsum[t] = tmp[t] - v;            // exclusive block bases
}

__global__ __launch_bounds__(256) void scan3_k(int* __restrict__ offs, int n,
                                               const int* __restrict__ bsum, int Etot) {
    int i = blockIdx.x * 256 + threadIdx.x;
    if (i < n) offs[i] += bsum[blockIdx.x];
    if (i == 0) offs[n] = Etot;
}

__global__ __launch_bounds__(256) void scatter2_k(const int* __restrict__ eiA, const int* __restrict__ eiB,
                                                  int E, const int* __restrict__ offs,
                                                  int* __restrict__ cursor, int* __restrict__ ssrc, int N) {
    int i = blockIdx.x * 256 + threadIdx.x;
    if (i < E) {
        int s = eiA[i], d = eiA[E + i];
        int p = offs[d] + atomicAdd(&cursor[d], 1);
        ssrc[p] = s;
    } else if (i < 2 * E) {
        int j = i - E;
        int s = eiB[j], d = eiB[E + j];
        int g = N + d;
        int p = offs[g] + atomicAdd(&cursor[g], 1);
        ssrc[p] = s;
    }
}

// ---------------- decision MLP: 16 nodes/block, gemm-style (4 rows/thread) ----------------

__global__ __launch_bounds__(256) void dec2_k(const float* __restrict__ X,
                                              const float* __restrict__ dw1, const float* __restrict__ db1,
                                              const float* __restrict__ dw2, const float* __restrict__ db2,
                                              float* __restrict__ wdec) {
    __shared__ float xs[16][129];
    __shared__ float hid[16][65];
    __shared__ float lg[16][2];
    int n0 = blockIdx.x * 16;
    int tid = threadIdx.x;
    for (int idx = tid; idx < 16 * 128; idx += 256) {
        int r = idx >> 7, k = idx & 127;
        xs[r][k] = X[(n0 + r) * 128 + k];
    }
    __syncthreads();
    int c = tid & 63, g = tid >> 6;            // 4 groups x 4 rows
    float acc[4] = {0.f, 0.f, 0.f, 0.f};
    #pragma unroll 4
    for (int k = 0; k < 128; k++) {
        float w = dw1[k * 64 + c];
        #pragma unroll
        for (int r = 0; r < 4; r++) acc[r] += xs[g * 4 + r][k] * w;
    }
    float b = db1[c];
    #pragma unroll
    for (int r = 0; r < 4; r++) hid[g * 4 + r][c] = fmaxf(acc[r] + b, 0.f);
    __syncthreads();
    if (tid < 32) {
        int node = tid >> 1, o = tid & 1;
        float l = db2[o];
        #pragma unroll 4
        for (int j = 0; j < 64; j++) l += hid[node][j] * dw2[j * 2 + o];
        lg[node][o] = l;
    }
    __syncthreads();
    if (tid < 16) {
        float l0 = lg[tid][0], l1 = lg[tid][1];
        float mm = fmaxf(l0, l1);
        float e0 = __expf(l0 - mm), e1 = __expf(l1 - mm);
        float s = e0 + e1;
        wdec[(n0 + tid) * 2 + 0] = e0 / s;
        wdec[(n0 + tid) * 2 + 1] = e1 / s;
    }
}

// ---------------- fused GEMM (both types) + attention scalars ----------------
// HA = X@WA, HB = X@WB ; elX[n]=HX[n,:]@aX0, erX[n]=HX[n,:]@aX1

template <int M>
__global__ __launch_bounds__(256) void gemmatt_k(const float* __restrict__ X,
                                                 const float* __restrict__ WA, const float* __restrict__ WB,
                                                 const float* __restrict__ aA0, const float* __restrict__ aA1,
                                                 const float* __restrict__ aB0, const float* __restrict__ aB1,
                                                 float* __restrict__ HA, float* __restrict__ HB,
                                                 float* __restrict__ elA, float* __restrict__ erA,
                                                 float* __restrict__ elB, float* __restrict__ erB) {
    constexpr int K = 128;
    constexpr int NB = 16;
    constexpr int G = 256 / M;
    constexpr int R = NB / G;
    __shared__ float xs[NB][K + 1];
    int n0 = blockIdx.x * NB;
    int tid = threadIdx.x;
    for (int idx = tid; idx < NB * K; idx += 256) {
        int r = idx >> 7, k = idx & 127;
        xs[r][k] = X[(n0 + r) * K + k];
    }
    __syncthreads();
    const int c = tid % M;
    const int g = tid / M;
    float accA[R], accB[R];
    #pragma unroll
    for (int r = 0; r < R; r++) { accA[r] = 0.f; accB[r] = 0.f; }
    #pragma unroll 4
    for (int k = 0; k < K; k++) {
        float wA = WA[k * M + c];
        float wB = WB[k * M + c];
        #pragma unroll
        for (int r = 0; r < R; r++) {
            float xv = xs[g * R + r][k];
            accA[r] += xv * wA;
            accB[r] += xv * wB;
        }
    }
    #pragma unroll
    for (int r = 0; r < R; r++) {
        HA[(size_t)(n0 + g * R + r) * M + c] = accA[r];
        HB[(size_t)(n0 + g * R + r) * M + c] = accB[r];
    }
    // ---- attention scalar reductions (reuse xs as scratch) ----
    int row = tid >> 4, lane = tid & 15;
    #pragma unroll
    for (int pass = 0; pass < 4; pass++) {
        const float* av = (pass == 0) ? aA0 : (pass == 1) ? aA1 : (pass == 2) ? aB0 : aB1;
        float* dst      = (pass == 0) ? elA : (pass == 1) ? erA : (pass == 2) ? elB : erB;
        float avc = av[c];
        __syncthreads();
        #pragma unroll
        for (int r = 0; r < R; r++)
            xs[g * R + r][c] = ((pass < 2) ? accA[r] : accB[r]) * avc;
        __syncthreads();
        float s = 0.f;
        #pragma unroll
        for (int cc = lane; cc < M; cc += 16) s += xs[row][cc];
        #pragma unroll
        for (int o = 8; o > 0; o >>= 1) s += __shfl_down(s, o, 16);
        if (lane == 0) dst[n0 + row] = s;
    }
}

// ---------------- per-node GAT over BOTH types, blended + relu, no atomics ----------------

template <int F>
__global__ __launch_bounds__(256) void gat2_k(const int* __restrict__ offsAll, const int* __restrict__ ssrcAll,
                                              const float* __restrict__ elA, const float* __restrict__ erA,
                                              const float* __restrict__ elB, const float* __restrict__ erB,
                                              const float* __restrict__ HA, const float* __restrict__ HB,
                                              const float* __restrict__ wdec,
                                              float* __restrict__ out, int N) {
    constexpr int P = 256 / F;          // edge-partitions
    __shared__ int   sj[MAXDEG];
    __shared__ float ej[MAXDEG];
    __shared__ float red[256];
    int n = blockIdx.x;
    int tid = threadIdx.x;
    int feat = tid & (F - 1);
    int part = tid / F;
    int wave = tid >> 6, lane = tid & 63;
    float acc = 0.f;
    #pragma unroll
    for (int t = 0; t < 2; t++) {
        const int*   offs = offsAll + t * N;
        const float* el = t ? elB : elA;
        const float* er = t ? erB : erA;
        const float* H  = t ? HB  : HA;
        int beg = offs[n];
        int deg = offs[n + 1] - beg;
        if (deg > MAXDEG) deg = MAXDEG;
        float ern = er[n];
        __syncthreads();                              // sj/ej reuse barrier
        for (int j = tid; j < deg; j += 256) {
            int s = ssrcAll[beg + j];
            sj[j] = s;
            float e = el[s] + ern;
            ej[j] = (e > 0.f) ? e : 0.2f * e;
        }
        __syncthreads();
        // segment max: wave shuffle + cross-wave LDS
        float m = -1e30f;
        for (int j = tid; j < deg; j += 256) m = fmaxf(m, ej[j]);
        #pragma unroll
        for (int o = 32; o > 0; o >>= 1) m = fmaxf(m, __shfl_xor(m, o));
        if (lane == 0) red[wave] = m;
        __syncthreads();
        m = fmaxf(fmaxf(red[0], red[1]), fmaxf(red[2], red[3]));
        __syncthreads();
        // exp + segment sum
        float ssum = 0.f;
        for (int j = tid; j < deg; j += 256) {
            float ex = __expf(ej[j] - m);
            ej[j] = ex;
            ssum += ex;
        }
        #pragma unroll
        for (int o = 32; o > 0; o >>= 1) ssum += __shfl_xor(ssum, o);
        if (lane == 0) red[wave] = ssum;
        __syncthreads();
        float tot = red[0] + red[1] + red[2] + red[3];
        float coef = wdec[n * 2 + t] / (tot + 1e-9f);
        // weighted gather: partition edges among P sub-groups
        float a = 0.f;
        for (int j = part; j < deg; j += P) a += ej[j] * H[(size_t)sj[j] * F + feat];
        acc += coef * a;
    }
    __syncthreads();
    red[tid] = acc;
    __syncthreads();
    if (part == 0) {
        float s = acc;
        #pragma unroll
        for (int p = 1; p < P; p++) s += red[p * F + feat];
        out[(size_t)n * F + feat] = fmaxf(s, 0.f);
    }
}

// ---------------- head: 64 -> 32 relu -> 2 softmax ----------------

__global__ __launch_bounds__(256) void head_k(const float* __restrict__ H2,
                                              const float* __restrict__ fc1w, const float* __restrict__ fc1b,
                                              const float* __restrict__ fc2w, const float* __restrict__ fc2b,
                                              float* __restrict__ out, int N) {
    __shared__ float xs[4][64];
    __shared__ float hid[4][32];
    int n0 = blockIdx.x * 4;
    int sub = threadIdx.x >> 6, u = threadIdx.x & 63;
    for (int idx = threadIdx.x; idx < 4 * 64; idx += 256) {
        int r = idx >> 6, k = idx & 63;
        int n = n0 + r;
        xs[r][k] = (n < N) ? H2[n * 64 + k] : 0.f;
    }
    __syncthreads();
    if (u < 32) {
        float a = fc1b[u];
        #pragma unroll 4
        for (int k = 0; k < 64; k++) a += xs[sub][k] * fc1w[k * 32 + u];
        hid[sub][u] = fmaxf(a, 0.f);
    }
    __syncthreads();
    if (u == 0) {
        int n = n0 + sub;
        if (n < N) {
            float l0 = fc2b[0], l1 = fc2b[1];
            #pragma unroll 4
            for (int j = 0; j < 32; j++) {
                float h = hid[sub][j];
                l0 += h * fc2w[j * 2 + 0];
                l1 += h * fc2w[j * 2 + 1];
            }
            float mm = fmaxf(l0, l1);
            float e0 = __expf(l0 - mm), e1 = __expf(l1 - mm);
            float s = e0 + e1;
            out[n * 2 + 0] = e0 / s;
            out[n * 2 + 1] = e1 / s;
        }
    }
}

// ---------------- launch ----------------

extern "C" void kernel_launch(void* const* d_in, const int* in_sizes, int n_in,
                              void* d_out, int out_size, void* d_ws, size_t ws_size,
                              hipStream_t stream) {
    const float* x     = (const float*)d_in[0];
    const int*   eiA   = (const int*)d_in[1];
    const int*   eiB   = (const int*)d_in[2];
    const float* W1    = (const float*)d_in[3];
    const float* a1    = (const float*)d_in[4];
    const float* d1w1  = (const float*)d_in[5];
    const float* d1b1  = (const float*)d_in[6];
    const float* d1w2  = (const float*)d_in[7];
    const float* d1b2  = (const float*)d_in[8];
    const float* W2    = (const float*)d_in[9];
    const float* a2    = (const float*)d_in[10];
    const float* d2w1  = (const float*)d_in[11];
    const float* d2b1  = (const float*)d_in[12];
    const float* d2w2  = (const float*)d_in[13];
    const float* d2b2  = (const float*)d_in[14];
    const float* fc1w  = (const float*)d_in[15];
    const float* fc1b  = (const float*)d_in[16];
    const float* fc2w  = (const float*)d_in[17];
    const float* fc2b  = (const float*)d_in[18];
    float* out = (float*)d_out;

    const int N = NN, E = EE;

    char* ws = (char*)d_ws;
    size_t off = 0;
    auto alloc = [&](size_t bytes) -> char* {
        char* p = ws + off;
        off = (off + bytes + 255) & ~(size_t)255;
        return p;
    };
    int*   cntAll  = (int*)alloc((size_t)2 * N * sizeof(int));
    int*   offsAll = (int*)alloc(((size_t)2 * N + 1) * sizeof(int));
    int*   ssrcAll = (int*)alloc((size_t)2 * E * sizeof(int));
    int*   bsum    = (int*)alloc(1024 * sizeof(int));
    float* wdec    = (float*)alloc((size_t)N * 2 * sizeof(float));
    float* elA     = (float*)alloc(N * sizeof(float));
    float* erA     = (float*)alloc(N * sizeof(float));
    float* elB     = (float*)alloc(N * sizeof(float));
    float* erB     = (float*)alloc(N * sizeof(float));
    float* hA      = (float*)alloc((size_t)N * 128 * sizeof(float));
    float* hB      = (float*)alloc((size_t)N * 128 * sizeof(float));
    float* hOut1   = (float*)alloc((size_t)N * 128 * sizeof(float));
    float* hOut2   = (float*)alloc((size_t)N * 64 * sizeof(float));

    const int twoN = 2 * N, twoE = 2 * E;
    const int nScanBlocks = (twoN + 255) / 256;     // 313
    const int nEdgeBlocks = (twoE + 255) / 256;

    // ---- CSR build (both types in one chain) ----
    hipMemsetAsync(cntAll, 0, (size_t)twoN * sizeof(int), stream);
    hist2_k<<<nEdgeBlocks, 256, 0, stream>>>(eiA + E, eiB + E, E, cntAll, N);
    scan1_k<<<nScanBlocks, 256, 0, stream>>>(cntAll, twoN, offsAll, bsum);
    scan2_k<<<1, 512, 0, stream>>>(bsum, nScanBlocks);
    scan3_k<<<nScanBlocks, 256, 0, stream>>>(offsAll, twoN, bsum, twoE);
    hipMemsetAsync(cntAll, 0, (size_t)twoN * sizeof(int), stream);
    scatter2_k<<<nEdgeBlocks, 256, 0, stream>>>(eiA, eiB, E, offsAll, cntAll, ssrcAll, N);

    // ---- Layer 1 ----
    dec2_k<<<N / 16, 256, 0, stream>>>(x, d1w1, d1b1, d1w2, d1b2, wdec);
    gemmatt_k<128><<<N / 16, 256, 0, stream>>>(x, W1, W1 + 128 * 128,
                                               a1, a1 + 128, a1 + 2 * 128, a1 + 3 * 128,
                                               hA, hB, elA, erA, elB, erB);
    gat2_k<128><<<N, 256, 0, stream>>>(offsAll, ssrcAll, elA, erA, elB, erB, hA, hB, wdec, hOut1, N);

    // ---- Layer 2 ----
    dec2_k<<<N / 16, 256, 0, stream>>>(hOut1, d2w1, d2b1, d2w2, d2b2, wdec);
    gemmatt_k<64><<<N / 16, 256, 0, stream>>>(hOut1, W2, W2 + 128 * 64,
                                              a2, a2 + 64, a2 + 2 * 64, a2 + 3 * 64,
                                              hA, hB, elA, erA, elB, erB);
    gat2_k<64><<<N, 256, 0, stream>>>(offsAll, ssrcAll, elA, erA, elB, erB, hA, hB, wdec, hOut2, N);

    // ---- head ----
    head_k<<<(N + 3) / 4, 256, 0, stream>>>(hOut2, fc1w, fc1b, fc2w, fc2b, out, N);
}

// Round 3
// 514.807 us; speedup vs baseline: 1.4959x; 1.4057x over previous
//
#include <hip/hip_runtime.h>
#include <hip/hip_bf16.h>

#define NN   40000
#define EE   640000

// ---------------- CSR build (both edge types concatenated: cnt[2N], offs[2N+1], ssrc[2E]) ----------------

__global__ __launch_bounds__(256) void hist2_k(const int* __restrict__ dstA, const int* __restrict__ dstB,
                                               int E, int* __restrict__ cnt, int N) {
    int i = blockIdx.x * 256 + threadIdx.x;
    if (i < E)            atomicAdd(&cnt[dstA[i]], 1);
    else if (i < 2 * E)   atomicAdd(&cnt[N + dstB[i - E]], 1);
}

__global__ __launch_bounds__(256) void scan1_k(const int* __restrict__ cnt, int n,
                                               int* __restrict__ offs, int* __restrict__ bsum) {
    __shared__ int tmp[256];
    int i = blockIdx.x * 256 + threadIdx.x;
    int v = (i < n) ? cnt[i] : 0;
    tmp[threadIdx.x] = v;
    __syncthreads();
    for (int d = 1; d < 256; d <<= 1) {
        int t = (threadIdx.x >= d) ? tmp[threadIdx.x - d] : 0;
        __syncthreads();
        tmp[threadIdx.x] += t;
        __syncthreads();
    }
    if (i < n) offs[i] = tmp[threadIdx.x] - v;   // exclusive
    if (threadIdx.x == 255) bsum[blockIdx.x] = tmp[255];
}

__global__ __launch_bounds__(512) void scan2_k(int* __restrict__ bsum, int nb) {
    __shared__ int tmp[512];
    int t = threadIdx.x;
    int v = (t < nb) ? bsum[t] : 0;
    tmp[t] = v;
    __syncthreads();
    for (int d = 1; d < 512; d <<= 1) {
        int x = (t >= d) ? tmp[t - d] : 0;
        __syncthreads();
        tmp[t] += x;
        __syncthreads();
    }
    if (t < nb) bsum[t] = tmp[t] - v;            // exclusive block bases
}

__global__ __launch_bounds__(256) void scan3_k(int* __restrict__ offs, int n,
                                               const int* __restrict__ bsum, int Etot) {
    int i = blockIdx.x * 256 + threadIdx.x;
    if (i < n) offs[i] += bsum[blockIdx.x];
    if (i == 0) offs[n] = Etot;
}

__global__ __launch_bounds__(256) void scatter2_k(const int* __restrict__ eiA, const int* __restrict__ eiB,
                                                  int E, const int* __restrict__ offs,
                                                  int* __restrict__ cursor, int* __restrict__ ssrc, int N) {
    int i = blockIdx.x * 256 + threadIdx.x;
    if (i < E) {
        int s = eiA[i], d = eiA[E + i];
        int p = offs[d] + atomicAdd(&cursor[d], 1);
        ssrc[p] = s;
    } else if (i < 2 * E) {
        int j = i - E;
        int s = eiB[j], d = eiB[E + j];
        int g = N + d;
        int p = offs[g] + atomicAdd(&cursor[g], 1);
        ssrc[p] = s;
    }
}

// ---------------- fused: GEMM (both types, bf16 out) + attention scalars + decision MLP ----------------

template <int M>
__global__ __launch_bounds__(256) void fusedgemm_k(const float* __restrict__ X,
                                                   const float* __restrict__ WA, const float* __restrict__ WB,
                                                   const float* __restrict__ aA0, const float* __restrict__ aA1,
                                                   const float* __restrict__ aB0, const float* __restrict__ aB1,
                                                   const float* __restrict__ dw1, const float* __restrict__ db1,
                                                   const float* __restrict__ dw2, const float* __restrict__ db2,
                                                   __hip_bfloat16* __restrict__ HbA, __hip_bfloat16* __restrict__ HbB,
                                                   float* __restrict__ elA, float* __restrict__ erA,
                                                   float* __restrict__ elB, float* __restrict__ erB,
                                                   float* __restrict__ wdec) {
    constexpr int K = 128;
    constexpr int NB = 16;
    constexpr int G = 256 / M;   // 2 (M=128) or 4 (M=64)
    constexpr int R = NB / G;    // 8 or 4
    __shared__ float xs[NB][K + 1];
    __shared__ float hid[NB][65];
    __shared__ float lg[16][2];
    int n0 = blockIdx.x * NB;
    int tid = threadIdx.x;
    for (int idx = tid; idx < NB * K; idx += 256) {
        int r = idx >> 7, k = idx & 127;
        xs[r][k] = X[(size_t)(n0 + r) * K + k];
    }
    __syncthreads();

    // ---- GEMM both types ----
    const int c = tid % M;
    const int g = tid / M;
    float accA[R], accB[R];
    #pragma unroll
    for (int r = 0; r < R; r++) { accA[r] = 0.f; accB[r] = 0.f; }
    #pragma unroll 4
    for (int k = 0; k < K; k++) {
        float wA = WA[k * M + c];
        float wB = WB[k * M + c];
        #pragma unroll
        for (int r = 0; r < R; r++) {
            float xv = xs[g * R + r][k];
            accA[r] += xv * wA;
            accB[r] += xv * wB;
        }
    }

    // ---- decision MLP (reads xs, so before xs scratch reuse) ----
    {
        int dc = tid & 63, dg = tid >> 6;      // 4 groups x 4 rows
        float da[4] = {0.f, 0.f, 0.f, 0.f};
        #pragma unroll 4
        for (int k = 0; k < 128; k++) {
            float w = dw1[k * 64 + dc];
            #pragma unroll
            for (int r = 0; r < 4; r++) da[r] += xs[dg * 4 + r][k] * w;
        }
        float b = db1[dc];
        #pragma unroll
        for (int r = 0; r < 4; r++) hid[dg * 4 + r][dc] = fmaxf(da[r] + b, 0.f);
    }
    __syncthreads();
    if (tid < 32) {
        int node = tid >> 1, o = tid & 1;
        float l = db2[o];
        #pragma unroll 4
        for (int j = 0; j < 64; j++) l += hid[node][j] * dw2[j * 2 + o];
        lg[node][o] = l;
    }
    __syncthreads();
    if (tid < 16) {
        float l0 = lg[tid][0], l1 = lg[tid][1];
        float mm = fmaxf(l0, l1);
        float e0 = __expf(l0 - mm), e1 = __expf(l1 - mm);
        float s = e0 + e1;
        wdec[(size_t)(n0 + tid) * 2 + 0] = e0 / s;
        wdec[(size_t)(n0 + tid) * 2 + 1] = e1 / s;
    }

    // ---- bf16 H stores ----
    #pragma unroll
    for (int r = 0; r < R; r++) {
        HbA[(size_t)(n0 + g * R + r) * M + c] = __float2bfloat16(accA[r]);
        HbB[(size_t)(n0 + g * R + r) * M + c] = __float2bfloat16(accB[r]);
    }

    // ---- attention scalars (reuse xs as scratch) ----
    int row = tid >> 4, lane16 = tid & 15;
    #pragma unroll
    for (int pass = 0; pass < 4; pass++) {
        const float* av = (pass == 0) ? aA0 : (pass == 1) ? aA1 : (pass == 2) ? aB0 : aB1;
        float* dst      = (pass == 0) ? elA : (pass == 1) ? erA : (pass == 2) ? elB : erB;
        float avc = av[c];
        __syncthreads();
        #pragma unroll
        for (int r = 0; r < R; r++)
            xs[g * R + r][c] = ((pass < 2) ? accA[r] : accB[r]) * avc;
        __syncthreads();
        float s = 0.f;
        #pragma unroll
        for (int cc = lane16; cc < M; cc += 16) s += xs[row][cc];
        #pragma unroll
        for (int o = 8; o > 0; o >>= 1) s += __shfl_down(s, o, 16);
        if (lane16 == 0) dst[n0 + row] = s;
    }
}

// ---------------- wave-per-node GAT: online softmax in registers, bf16 gather, optional fused head ----------------

template <int F, bool HEAD>
__global__ __launch_bounds__(256) void gat3_k(const int* __restrict__ offsAll, const int* __restrict__ ssrcAll,
                                              const float* __restrict__ elA, const float* __restrict__ erA,
                                              const float* __restrict__ elB, const float* __restrict__ erB,
                                              const unsigned int* __restrict__ HuA, const unsigned int* __restrict__ HuB,
                                              const float* __restrict__ wdec,
                                              float* __restrict__ outF,
                                              const float* __restrict__ fc1w, const float* __restrict__ fc1b,
                                              const float* __restrict__ fc2w, const float* __restrict__ fc2b,
                                              float* __restrict__ outP, int N) {
    __shared__ float hs[4][97];          // head scratch (wave-local)
    int wid = threadIdx.x >> 6, lane = threadIdx.x & 63;
    int n = blockIdx.x * 4 + wid;
    if (n >= N) return;

    float acc0 = 0.f, acc1 = 0.f;
    #pragma unroll
    for (int t = 0; t < 2; t++) {
        const int* offs = offsAll + t * N;
        int beg = offs[n];
        int deg = offs[n + 1] - beg;
        const float* el = t ? elB : elA;
        float ern = (t ? erB : erA)[n];
        const unsigned int* Hu = t ? HuB : HuA;
        float coef = wdec[(size_t)n * 2 + t];

        float m = -1e30f, ssum = 0.f, g0 = 0.f, g1 = 0.f;
        for (int c0 = 0; c0 < deg; c0 += 64) {
            int rem = deg - c0;
            int cl = rem < 64 ? rem : 64;
            int sv = 0; float ev = -1e30f;
            if (lane < cl) {
                sv = ssrcAll[beg + c0 + lane];
                float e = el[sv] + ern;
                ev = (e > 0.f) ? e : 0.2f * e;
            }
            float mc = ev;
            #pragma unroll
            for (int o = 32; o > 0; o >>= 1) mc = fmaxf(mc, __shfl_xor(mc, o));
            float newm = fmaxf(m, mc);
            float scale = __expf(m - newm);      // first chunk: exp(-inf)=0
            float ex = (lane < cl) ? __expf(ev - newm) : 0.f;
            float cs = ex;
            #pragma unroll
            for (int o = 32; o > 0; o >>= 1) cs += __shfl_xor(cs, o);
            ssum = ssum * scale + cs;
            g0 *= scale; g1 *= scale;
            if (F == 128) {
                #pragma unroll 4
                for (int j = 0; j < cl; j++) {
                    int s   = __shfl(sv, j);
                    float w = __shfl(ex, j);
                    unsigned int p = Hu[(size_t)s * 64 + lane];
                    g0 += w * __uint_as_float(p << 16);
                    g1 += w * __uint_as_float(p & 0xffff0000u);
                }
            } else {
                int half = lane >> 5, l5 = lane & 31;
                #pragma unroll 4
                for (int jj = 0; jj < cl; jj += 2) {
                    int j = (jj + half) & 63;
                    int s   = __shfl(sv, j);     // ex==0 guards any j >= cl
                    float w = __shfl(ex, j);
                    unsigned int p = Hu[(size_t)s * 32 + l5];
                    g0 += w * __uint_as_float(p << 16);
                    g1 += w * __uint_as_float(p & 0xffff0000u);
                }
            }
            m = newm;
        }
        if (F == 64) {                           // combine the two half-wave edge partitions
            g0 += __shfl_xor(g0, 32);
            g1 += __shfl_xor(g1, 32);
        }
        float inv = coef / (ssum + 1e-9f);
        acc0 += inv * g0;
        acc1 += inv * g1;
    }

    if (!HEAD) {
        float2 v;
        v.x = fmaxf(acc0, 0.f);
        v.y = fmaxf(acc1, 0.f);
        ((float2*)outF)[(size_t)n * (F / 2) + lane] = v;
    } else {
        // relu -> 64->32 relu -> 2 -> softmax, all wave-local
        int l5 = lane & 31;
        if (lane < 32) {
            hs[wid][2 * l5 + 0] = fmaxf(acc0, 0.f);
            hs[wid][2 * l5 + 1] = fmaxf(acc1, 0.f);
        }
        float h1 = 0.f;
        if (lane < 32) {
            h1 = fc1b[lane];
            #pragma unroll 4
            for (int k = 0; k < 64; k++) h1 += hs[wid][k] * fc1w[k * 32 + lane];
            hs[wid][64 + lane] = fmaxf(h1, 0.f);
        }
        if (lane < 2) {
            float l = fc2b[lane];
            #pragma unroll 4
            for (int j = 0; j < 32; j++) l += hs[wid][64 + j] * fc2w[j * 2 + lane];
            float lo = __shfl(l, 0), lhi = __shfl(l, 1);
            if (lane == 0) {
                float mm = fmaxf(lo, lhi);
                float e0 = __expf(lo - mm), e1 = __expf(lhi - mm);
                float s = e0 + e1;
                float2 pr; pr.x = e0 / s; pr.y = e1 / s;
                ((float2*)outP)[n] = pr;
            }
        }
    }
}

// ---------------- launch ----------------

extern "C" void kernel_launch(void* const* d_in, const int* in_sizes, int n_in,
                              void* d_out, int out_size, void* d_ws, size_t ws_size,
                              hipStream_t stream) {
    const float* x     = (const float*)d_in[0];
    const int*   eiA   = (const int*)d_in[1];
    const int*   eiB   = (const int*)d_in[2];
    const float* W1    = (const float*)d_in[3];
    const float* a1    = (const float*)d_in[4];
    const float* d1w1  = (const float*)d_in[5];
    const float* d1b1  = (const float*)d_in[6];
    const float* d1w2  = (const float*)d_in[7];
    const float* d1b2  = (const float*)d_in[8];
    const float* W2    = (const float*)d_in[9];
    const float* a2    = (const float*)d_in[10];
    const float* d2w1  = (const float*)d_in[11];
    const float* d2b1  = (const float*)d_in[12];
    const float* d2w2  = (const float*)d_in[13];
    const float* d2b2  = (const float*)d_in[14];
    const float* fc1w  = (const float*)d_in[15];
    const float* fc1b  = (const float*)d_in[16];
    const float* fc2w  = (const float*)d_in[17];
    const float* fc2b  = (const float*)d_in[18];
    float* out = (float*)d_out;

    const int N = NN, E = EE;

    char* ws = (char*)d_ws;
    size_t off = 0;
    auto alloc = [&](size_t bytes) -> char* {
        char* p = ws + off;
        off = (off + bytes + 255) & ~(size_t)255;
        return p;
    };
    int*   cntAll  = (int*)alloc((size_t)2 * N * sizeof(int));
    int*   offsAll = (int*)alloc(((size_t)2 * N + 1) * sizeof(int));
    int*   ssrcAll = (int*)alloc((size_t)2 * E * sizeof(int));
    int*   bsum    = (int*)alloc(1024 * sizeof(int));
    float* wdec    = (float*)alloc((size_t)N * 2 * sizeof(float));
    float* elA     = (float*)alloc(N * sizeof(float));
    float* erA     = (float*)alloc(N * sizeof(float));
    float* elB     = (float*)alloc(N * sizeof(float));
    float* erB     = (float*)alloc(N * sizeof(float));
    __hip_bfloat16* HbA = (__hip_bfloat16*)alloc((size_t)N * 128 * sizeof(__hip_bfloat16));
    __hip_bfloat16* HbB = (__hip_bfloat16*)alloc((size_t)N * 128 * sizeof(__hip_bfloat16));
    float* hOut1   = (float*)alloc((size_t)N * 128 * sizeof(float));

    const int twoN = 2 * N, twoE = 2 * E;
    const int nScanBlocks = (twoN + 255) / 256;
    const int nEdgeBlocks = (twoE + 255) / 256;

    // ---- CSR build (both types in one chain) ----
    hipMemsetAsync(cntAll, 0, (size_t)twoN * sizeof(int), stream);
    hist2_k<<<nEdgeBlocks, 256, 0, stream>>>(eiA + E, eiB + E, E, cntAll, N);
    scan1_k<<<nScanBlocks, 256, 0, stream>>>(cntAll, twoN, offsAll, bsum);
    scan2_k<<<1, 512, 0, stream>>>(bsum, nScanBlocks);
    scan3_k<<<nScanBlocks, 256, 0, stream>>>(offsAll, twoN, bsum, twoE);
    hipMemsetAsync(cntAll, 0, (size_t)twoN * sizeof(int), stream);
    scatter2_k<<<nEdgeBlocks, 256, 0, stream>>>(eiA, eiB, E, offsAll, cntAll, ssrcAll, N);

    // ---- Layer 1 ----
    fusedgemm_k<128><<<N / 16, 256, 0, stream>>>(x, W1, W1 + 128 * 128,
                                                 a1, a1 + 128, a1 + 2 * 128, a1 + 3 * 128,
                                                 d1w1, d1b1, d1w2, d1b2,
                                                 HbA, HbB, elA, erA, elB, erB, wdec);
    gat3_k<128, false><<<N / 4, 256, 0, stream>>>(offsAll, ssrcAll, elA, erA, elB, erB,
                                                  (const unsigned int*)HbA, (const unsigned int*)HbB,
                                                  wdec, hOut1,
                                                  nullptr, nullptr, nullptr, nullptr, nullptr, N);

    // ---- Layer 2 (head fused) ----
    fusedgemm_k<64><<<N / 16, 256, 0, stream>>>(hOut1, W2, W2 + 128 * 64,
                                                a2, a2 + 64, a2 + 2 * 64, a2 + 3 * 64,
                                                d2w1, d2b1, d2w2, d2b2,
                                                HbA, HbB, elA, erA, elB, erB, wdec);
    gat3_k<64, true><<<N / 4, 256, 0, stream>>>(offsAll, ssrcAll, elA, erA, elB, erB,
                                                (const unsigned int*)HbA, (const unsigned int*)HbB,
                                                wdec, nullptr,
                                                fc1w, fc1b, fc2w, fc2b, out, N);
}

// Round 5
// 467.737 us; speedup vs baseline: 1.6464x; 1.1006x over previous
//
#include <hip/hip_runtime.h>
#include <hip/hip_bf16.h>

#define NN   40000
#define EE   640000

// ---------------- CSR build (both edge types concatenated: cnt[2N], offs[2N+1], ssrc[2E]) ----------------

__global__ __launch_bounds__(256) void hist2_k(const int* __restrict__ dstA, const int* __restrict__ dstB,
                                               int E, int* __restrict__ cnt, int N) {
    int i = blockIdx.x * 256 + threadIdx.x;
    if (i < E)            atomicAdd(&cnt[dstA[i]], 1);
    else if (i < 2 * E)   atomicAdd(&cnt[N + dstB[i - E]], 1);
}

__global__ __launch_bounds__(256) void scan1_k(const int* __restrict__ cnt, int n,
                                               int* __restrict__ offs, int* __restrict__ bsum) {
    __shared__ int tmp[256];
    int i = blockIdx.x * 256 + threadIdx.x;
    int v = (i < n) ? cnt[i] : 0;
    tmp[threadIdx.x] = v;
    __syncthreads();
    for (int d = 1; d < 256; d <<= 1) {
        int t = (threadIdx.x >= d) ? tmp[threadIdx.x - d] : 0;
        __syncthreads();
        tmp[threadIdx.x] += t;
        __syncthreads();
    }
    if (i < n) offs[i] = tmp[threadIdx.x] - v;   // exclusive
    if (threadIdx.x == 255) bsum[blockIdx.x] = tmp[255];
}

__global__ __launch_bounds__(512) void scan2_k(int* __restrict__ bsum, int nb) {
    __shared__ int tmp[512];
    int t = threadIdx.x;
    int v = (t < nb) ? bsum[t] : 0;
    tmp[t] = v;
    __syncthreads();
    for (int d = 1; d < 512; d <<= 1) {
        int x = (t >= d) ? tmp[t - d] : 0;
        __syncthreads();
        tmp[t] += x;
        __syncthreads();
    }
    if (t < nb) bsum[t] = tmp[t] - v;            // exclusive block bases
}

__global__ __launch_bounds__(256) void scan3_k(int* __restrict__ offs, int n,
                                               const int* __restrict__ bsum, int Etot) {
    int i = blockIdx.x * 256 + threadIdx.x;
    if (i < n) offs[i] += bsum[blockIdx.x];
    if (i == 0) offs[n] = Etot;
}

__global__ __launch_bounds__(256) void scatter2_k(const int* __restrict__ eiA, const int* __restrict__ eiB,
                                                  int E, const int* __restrict__ offs,
                                                  int* __restrict__ cursor, int* __restrict__ ssrc, int N) {
    int i = blockIdx.x * 256 + threadIdx.x;
    if (i < E) {
        int s = eiA[i], d = eiA[E + i];
        int p = offs[d] + atomicAdd(&cursor[d], 1);
        ssrc[p] = s;
    } else if (i < 2 * E) {
        int j = i - E;
        int s = eiB[j], d = eiB[E + j];
        int g = N + d;
        int p = offs[g] + atomicAdd(&cursor[g], 1);
        ssrc[p] = s;
    }
}

// ---------------- fused: GEMM (both types, bf16 out) + attention scalars + decision MLP ----------------

template <int M>
__global__ __launch_bounds__(256) void fusedgemm_k(const float* __restrict__ X,
                                                   const float* __restrict__ WA, const float* __restrict__ WB,
                                                   const float* __restrict__ aA0, const float* __restrict__ aA1,
                                                   const float* __restrict__ aB0, const float* __restrict__ aB1,
                                                   const float* __restrict__ dw1, const float* __restrict__ db1,
                                                   const float* __restrict__ dw2, const float* __restrict__ db2,
                                                   __hip_bfloat16* __restrict__ HbA, __hip_bfloat16* __restrict__ HbB,
                                                   float* __restrict__ elA, float* __restrict__ erA,
                                                   float* __restrict__ elB, float* __restrict__ erB,
                                                   float* __restrict__ wdec) {
    constexpr int K = 128;
    constexpr int NB = 16;
    constexpr int G = 256 / M;   // 2 (M=128) or 4 (M=64)
    constexpr int R = NB / G;    // 8 or 4
    __shared__ float xs[NB][K + 1];
    __shared__ float hid[NB][65];
    __shared__ float lg[16][2];
    int n0 = blockIdx.x * NB;
    int tid = threadIdx.x;
    for (int idx = tid; idx < NB * K; idx += 256) {
        int r = idx >> 7, k = idx & 127;
        xs[r][k] = X[(size_t)(n0 + r) * K + k];
    }
    __syncthreads();

    // ---- GEMM both types ----
    const int c = tid % M;
    const int g = tid / M;
    float accA[R], accB[R];
    #pragma unroll
    for (int r = 0; r < R; r++) { accA[r] = 0.f; accB[r] = 0.f; }
    #pragma unroll 4
    for (int k = 0; k < K; k++) {
        float wA = WA[k * M + c];
        float wB = WB[k * M + c];
        #pragma unroll
        for (int r = 0; r < R; r++) {
            float xv = xs[g * R + r][k];
            accA[r] += xv * wA;
            accB[r] += xv * wB;
        }
    }

    // ---- decision MLP ----
    {
        int dc = tid & 63, dg = tid >> 6;      // 4 groups x 4 rows
        float da[4] = {0.f, 0.f, 0.f, 0.f};
        #pragma unroll 4
        for (int k = 0; k < 128; k++) {
            float w = dw1[k * 64 + dc];
            #pragma unroll
            for (int r = 0; r < 4; r++) da[r] += xs[dg * 4 + r][k] * w;
        }
        float b = db1[dc];
        #pragma unroll
        for (int r = 0; r < 4; r++) hid[dg * 4 + r][dc] = fmaxf(da[r] + b, 0.f);
    }
    __syncthreads();
    if (tid < 32) {
        int node = tid >> 1, o = tid & 1;
        float l = db2[o];
        #pragma unroll 4
        for (int j = 0; j < 64; j++) l += hid[node][j] * dw2[j * 2 + o];
        lg[node][o] = l;
    }
    __syncthreads();
    if (tid < 16) {
        float l0 = lg[tid][0], l1 = lg[tid][1];
        float mm = fmaxf(l0, l1);
        float e0 = __expf(l0 - mm), e1 = __expf(l1 - mm);
        float s = e0 + e1;
        wdec[(size_t)(n0 + tid) * 2 + 0] = e0 / s;
        wdec[(size_t)(n0 + tid) * 2 + 1] = e1 / s;
    }

    // ---- bf16 H stores ----
    #pragma unroll
    for (int r = 0; r < R; r++) {
        HbA[(size_t)(n0 + g * R + r) * M + c] = __float2bfloat16(accA[r]);
        HbB[(size_t)(n0 + g * R + r) * M + c] = __float2bfloat16(accB[r]);
    }

    // ---- attention scalars (reuse xs as scratch) ----
    int row = tid >> 4, lane16 = tid & 15;
    #pragma unroll
    for (int pass = 0; pass < 4; pass++) {
        const float* av = (pass == 0) ? aA0 : (pass == 1) ? aA1 : (pass == 2) ? aB0 : aB1;
        float* dst      = (pass == 0) ? elA : (pass == 1) ? erA : (pass == 2) ? elB : erB;
        float avc = av[c];
        __syncthreads();
        #pragma unroll
        for (int r = 0; r < R; r++)
            xs[g * R + r][c] = ((pass < 2) ? accA[r] : accB[r]) * avc;
        __syncthreads();
        float s = 0.f;
        #pragma unroll
        for (int cc = lane16; cc < M; cc += 16) s += xs[row][cc];
        #pragma unroll
        for (int o = 8; o > 0; o >>= 1) s += __shfl_down(s, o, 16);
        if (lane16 == 0) dst[n0 + row] = s;
    }
}

// ---------------- wave-per-node GAT v4: two-pass softmax, LDS-broadcast pipelined gather ----------------
// N assumed divisible by 4 (N=40000): no early exit, barriers are uniform.

template <int F, bool HEAD>
__global__ __launch_bounds__(256) void gat4_k(const int* __restrict__ offsAll, const int* __restrict__ ssrcAll,
                                              const float* __restrict__ elA, const float* __restrict__ erA,
                                              const float* __restrict__ elB, const float* __restrict__ erB,
                                              const unsigned* __restrict__ HuA, const unsigned* __restrict__ HuB,
                                              const float* __restrict__ wdec,
                                              float* __restrict__ outF,
                                              const float* __restrict__ fc1w, const float* __restrict__ fc1b,
                                              const float* __restrict__ fc2w, const float* __restrict__ fc2b,
                                              float* __restrict__ outP, int N) {
    constexpr int MAXD = 128;                   // Poisson(16): P(deg>128) ~ 1e-80, safe clamp
    __shared__ uint2 se[4][MAXD];               // (src, exBits), wave-private slice
    __shared__ float hs[4][97];                 // head scratch
    const int wid = threadIdx.x >> 6, lane = threadIdx.x & 63;
    const int n = blockIdx.x * 4 + wid;
    const int l5 = lane & 31, sub = lane >> 5;
    float acc0 = 0.f, acc1 = 0.f;

    #pragma unroll
    for (int t = 0; t < 2; t++) {
        const int* offs = offsAll + t * N;
        int beg = offs[n];
        int deg = offs[n + 1] - beg;
        if (deg > MAXD) deg = MAXD;
        const float* el = t ? elB : elA;
        float ern = (t ? erB : erA)[n];
        const unsigned* Hu = t ? HuB : HuA;
        float coef = wdec[(size_t)n * 2 + t];

        __syncthreads();                        // protect previous iteration's se reads
        // pass 1: load src, raw attention value (regs only)
        int sreg[2]; float ereg[2];
        float mx = -1e30f;
        #pragma unroll
        for (int k = 0; k < 2; k++) {
            int j = lane + 64 * k;
            if (j < deg) {
                int s = ssrcAll[beg + j];
                float e = el[s] + ern;
                e = (e > 0.f) ? e : 0.2f * e;
                sreg[k] = s; ereg[k] = e;
                mx = fmaxf(mx, e);
            }
        }
        #pragma unroll
        for (int o = 32; o > 0; o >>= 1) mx = fmaxf(mx, __shfl_xor(mx, o));
        // pass 2: exp, write (src,ex) to LDS, sum
        float sum = 0.f;
        #pragma unroll
        for (int k = 0; k < 2; k++) {
            int j = lane + 64 * k;
            if (j < deg) {
                float ex = __expf(ereg[k] - mx);
                se[wid][j] = make_uint2((unsigned)sreg[k], __float_as_uint(ex));
                sum += ex;
            }
        }
        #pragma unroll
        for (int o = 32; o > 0; o >>= 1) sum += __shfl_xor(sum, o);
        float inv = coef / (sum + 1e-9f);
        __syncthreads();                        // ex visible to all lanes

        // pass 3: pipelined gather, uniform LDS broadcast (no cross-lane shuffles)
        float g0 = 0.f, g1 = 0.f;
        if (F == 128) {
            int j = 0;
            for (; j + 4 <= deg; j += 4) {
                uint2 p0 = se[wid][j], p1 = se[wid][j + 1], p2 = se[wid][j + 2], p3 = se[wid][j + 3];
                unsigned h0 = Hu[(size_t)p0.x * 64 + lane];
                unsigned h1 = Hu[(size_t)p1.x * 64 + lane];
                unsigned h2 = Hu[(size_t)p2.x * 64 + lane];
                unsigned h3 = Hu[(size_t)p3.x * 64 + lane];
                float w0 = __uint_as_float(p0.y), w1 = __uint_as_float(p1.y);
                float w2 = __uint_as_float(p2.y), w3 = __uint_as_float(p3.y);
                g0 = fmaf(w0, __uint_as_float(h0 << 16), g0);
                g1 = fmaf(w0, __uint_as_float(h0 & 0xffff0000u), g1);
                g0 = fmaf(w1, __uint_as_float(h1 << 16), g0);
                g1 = fmaf(w1, __uint_as_float(h1 & 0xffff0000u), g1);
                g0 = fmaf(w2, __uint_as_float(h2 << 16), g0);
                g1 = fmaf(w2, __uint_as_float(h2 & 0xffff0000u), g1);
                g0 = fmaf(w3, __uint_as_float(h3 << 16), g0);
                g1 = fmaf(w3, __uint_as_float(h3 & 0xffff0000u), g1);
            }
            for (; j < deg; j++) {
                uint2 p = se[wid][j];
                unsigned h = Hu[(size_t)p.x * 64 + lane];
                float w = __uint_as_float(p.y);
                g0 = fmaf(w, __uint_as_float(h << 16), g0);
                g1 = fmaf(w, __uint_as_float(h & 0xffff0000u), g1);
            }
        } else {
            // half-wave per edge: sub 0 -> even edges, sub 1 -> odd edges; combined at the very end
            int j = sub;
            for (; j + 7 <= deg; j += 8) {
                uint2 p0 = se[wid][j], p1 = se[wid][j + 2], p2 = se[wid][j + 4], p3 = se[wid][j + 6];
                unsigned h0 = Hu[(size_t)p0.x * 32 + l5];
                unsigned h1 = Hu[(size_t)p1.x * 32 + l5];
                unsigned h2 = Hu[(size_t)p2.x * 32 + l5];
                unsigned h3 = Hu[(size_t)p3.x * 32 + l5];
                float w0 = __uint_as_float(p0.y), w1 = __uint_as_float(p1.y);
                float w2 = __uint_as_float(p2.y), w3 = __uint_as_float(p3.y);
                g0 = fmaf(w0, __uint_as_float(h0 << 16), g0);
                g1 = fmaf(w0, __uint_as_float(h0 & 0xffff0000u), g1);
                g0 = fmaf(w1, __uint_as_float(h1 << 16), g0);
                g1 = fmaf(w1, __uint_as_float(h1 & 0xffff0000u), g1);
                g0 = fmaf(w2, __uint_as_float(h2 << 16), g0);
                g1 = fmaf(w2, __uint_as_float(h2 & 0xffff0000u), g1);
                g0 = fmaf(w3, __uint_as_float(h3 << 16), g0);
                g1 = fmaf(w3, __uint_as_float(h3 & 0xffff0000u), g1);
            }
            for (; j < deg; j += 2) {
                uint2 p = se[wid][j];
                unsigned h = Hu[(size_t)p.x * 32 + l5];
                float w = __uint_as_float(p.y);
                g0 = fmaf(w, __uint_as_float(h << 16), g0);
                g1 = fmaf(w, __uint_as_float(h & 0xffff0000u), g1);
            }
        }
        acc0 = fmaf(inv, g0, acc0);
        acc1 = fmaf(inv, g1, acc1);
    }

    if (F == 64) {                              // combine the two half-wave edge partitions
        acc0 += __shfl_xor(acc0, 32);
        acc1 += __shfl_xor(acc1, 32);
    }

    if (!HEAD) {
        float2 v;
        v.x = fmaxf(acc0, 0.f);
        v.y = fmaxf(acc1, 0.f);
        ((float2*)outF)[(size_t)n * (F / 2) + lane] = v;
    } else {
        // relu -> 64->32 relu -> 2 -> softmax, wave-local
        if (lane < 32) {
            hs[wid][2 * l5 + 0] = fmaxf(acc0, 0.f);
            hs[wid][2 * l5 + 1] = fmaxf(acc1, 0.f);
        }
        if (lane < 32) {
            float h1 = fc1b[lane];
            #pragma unroll 4
            for (int k = 0; k < 64; k++) h1 += hs[wid][k] * fc1w[k * 32 + lane];
            hs[wid][64 + lane] = fmaxf(h1, 0.f);
        }
        if (lane < 2) {
            float l = fc2b[lane];
            #pragma unroll 4
            for (int j = 0; j < 32; j++) l += hs[wid][64 + j] * fc2w[j * 2 + lane];
            float lo = __shfl(l, 0), lhi = __shfl(l, 1);
            if (lane == 0) {
                float mm = fmaxf(lo, lhi);
                float e0 = __expf(lo - mm), e1 = __expf(lhi - mm);
                float s = e0 + e1;
                float2 pr; pr.x = e0 / s; pr.y = e1 / s;
                ((float2*)outP)[n] = pr;
            }
        }
    }
}

// ---------------- launch ----------------

extern "C" void kernel_launch(void* const* d_in, const int* in_sizes, int n_in,
                              void* d_out, int out_size, void* d_ws, size_t ws_size,
                              hipStream_t stream) {
    const float* x     = (const float*)d_in[0];
    const int*   eiA   = (const int*)d_in[1];
    const int*   eiB   = (const int*)d_in[2];
    const float* W1    = (const float*)d_in[3];
    const float* a1    = (const float*)d_in[4];
    const float* d1w1  = (const float*)d_in[5];
    const float* d1b1  = (const float*)d_in[6];
    const float* d1w2  = (const float*)d_in[7];
    const float* d1b2  = (const float*)d_in[8];
    const float* W2    = (const float*)d_in[9];
    const float* a2    = (const float*)d_in[10];
    const float* d2w1  = (const float*)d_in[11];
    const float* d2b1  = (const float*)d_in[12];
    const float* d2w2  = (const float*)d_in[13];
    const float* d2b2  = (const float*)d_in[14];
    const float* fc1w  = (const float*)d_in[15];
    const float* fc1b  = (const float*)d_in[16];
    const float* fc2w  = (const float*)d_in[17];
    const float* fc2b  = (const float*)d_in[18];
    float* out = (float*)d_out;

    const int N = NN, E = EE;

    char* ws = (char*)d_ws;
    size_t off = 0;
    auto alloc = [&](size_t bytes) -> char* {
        char* p = ws + off;
        off = (off + bytes + 255) & ~(size_t)255;
        return p;
    };
    int*   cntAll    = (int*)alloc((size_t)2 * N * sizeof(int));   // adjacent to cursorAll:
    int*   cursorAll = (int*)alloc((size_t)2 * N * sizeof(int));   // one memset covers both
    int*   offsAll   = (int*)alloc(((size_t)2 * N + 1) * sizeof(int));
    int*   ssrcAll   = (int*)alloc((size_t)2 * E * sizeof(int));
    int*   bsum      = (int*)alloc(1024 * sizeof(int));
    float* wdec      = (float*)alloc((size_t)N * 2 * sizeof(float));
    float* elA       = (float*)alloc(N * sizeof(float));
    float* erA       = (float*)alloc(N * sizeof(float));
    float* elB       = (float*)alloc(N * sizeof(float));
    float* erB       = (float*)alloc(N * sizeof(float));
    __hip_bfloat16* HbA = (__hip_bfloat16*)alloc((size_t)N * 128 * sizeof(__hip_bfloat16));
    __hip_bfloat16* HbB = (__hip_bfloat16*)alloc((size_t)N * 128 * sizeof(__hip_bfloat16));
    float* hOut1     = (float*)alloc((size_t)N * 128 * sizeof(float));

    const int twoN = 2 * N, twoE = 2 * E;
    const int nScanBlocks = (twoN + 255) / 256;
    const int nEdgeBlocks = (twoE + 255) / 256;

    // ---- CSR build (both types in one chain) ----
    hipMemsetAsync(cntAll, 0, (size_t)4 * N * sizeof(int), stream);   // cnt + cursor
    hist2_k<<<nEdgeBlocks, 256, 0, stream>>>(eiA + E, eiB + E, E, cntAll, N);
    scan1_k<<<nScanBlocks, 256, 0, stream>>>(cntAll, twoN, offsAll, bsum);
    scan2_k<<<1, 512, 0, stream>>>(bsum, nScanBlocks);
    scan3_k<<<nScanBlocks, 256, 0, stream>>>(offsAll, twoN, bsum, twoE);
    scatter2_k<<<nEdgeBlocks, 256, 0, stream>>>(eiA, eiB, E, offsAll, cursorAll, ssrcAll, N);

    // ---- Layer 1 ----
    fusedgemm_k<128><<<N / 16, 256, 0, stream>>>(x, W1, W1 + 128 * 128,
                                                 a1, a1 + 128, a1 + 2 * 128, a1 + 3 * 128,
                                                 d1w1, d1b1, d1w2, d1b2,
                                                 HbA, HbB, elA, erA, elB, erB, wdec);
    gat4_k<128, false><<<N / 4, 256, 0, stream>>>(offsAll, ssrcAll, elA, erA, elB, erB,
                                                  (const unsigned*)HbA, (const unsigned*)HbB,
                                                  wdec, hOut1,
                                                  nullptr, nullptr, nullptr, nullptr, nullptr, N);

    // ---- Layer 2 (head fused) ----
    fusedgemm_k<64><<<N / 16, 256, 0, stream>>>(hOut1, W2, W2 + 128 * 64,
                                                a2, a2 + 64, a2 + 2 * 64, a2 + 3 * 64,
                                                d2w1, d2b1, d2w2, d2b2,
                                                HbA, HbB, elA, erA, elB, erB, wdec);
    gat4_k<64, true><<<N / 4, 256, 0, stream>>>(offsAll, ssrcAll, elA, erA, elB, erB,
                                                (const unsigned*)HbA, (const unsigned*)HbB,
                                                wdec, nullptr,
                                                fc1w, fc1b, fc2w, fc2b, out, N);
}

// Round 6
// 458.712 us; speedup vs baseline: 1.6788x; 1.0197x over previous
//
#include <hip/hip_runtime.h>
#include <hip/hip_bf16.h>

#define NN   40000
#define EE   640000

// ---------------- CSR build (both edge types concatenated: cnt[2N], offs[2N+1], ssrc[2E]) ----------------

__global__ __launch_bounds__(256) void hist2_k(const int* __restrict__ dstA, const int* __restrict__ dstB,
                                               int E, int* __restrict__ cnt, int N) {
    int i = blockIdx.x * 256 + threadIdx.x;
    if (i < E)            atomicAdd(&cnt[dstA[i]], 1);
    else if (i < 2 * E)   atomicAdd(&cnt[N + dstB[i - E]], 1);
}

__global__ __launch_bounds__(256) void scan1_k(const int* __restrict__ cnt, int n,
                                               int* __restrict__ offs, int* __restrict__ bsum) {
    __shared__ int tmp[256];
    int i = blockIdx.x * 256 + threadIdx.x;
    int v = (i < n) ? cnt[i] : 0;
    tmp[threadIdx.x] = v;
    __syncthreads();
    for (int d = 1; d < 256; d <<= 1) {
        int t = (threadIdx.x >= d) ? tmp[threadIdx.x - d] : 0;
        __syncthreads();
        tmp[threadIdx.x] += t;
        __syncthreads();
    }
    if (i < n) offs[i] = tmp[threadIdx.x] - v;   // exclusive
    if (threadIdx.x == 255) bsum[blockIdx.x] = tmp[255];
}

__global__ __launch_bounds__(512) void scan2_k(int* __restrict__ bsum, int nb) {
    __shared__ int tmp[512];
    int t = threadIdx.x;
    int v = (t < nb) ? bsum[t] : 0;
    tmp[t] = v;
    __syncthreads();
    for (int d = 1; d < 512; d <<= 1) {
        int x = (t >= d) ? tmp[t - d] : 0;
        __syncthreads();
        tmp[t] += x;
        __syncthreads();
    }
    if (t < nb) bsum[t] = tmp[t] - v;            // exclusive block bases
}

__global__ __launch_bounds__(256) void scan3_k(int* __restrict__ offs, int n,
                                               const int* __restrict__ bsum, int Etot) {
    int i = blockIdx.x * 256 + threadIdx.x;
    if (i < n) offs[i] += bsum[blockIdx.x];
    if (i == 0) offs[n] = Etot;
}

__global__ __launch_bounds__(256) void scatter2_k(const int* __restrict__ eiA, const int* __restrict__ eiB,
                                                  int E, const int* __restrict__ offs,
                                                  int* __restrict__ cursor, int* __restrict__ ssrc, int N) {
    int i = blockIdx.x * 256 + threadIdx.x;
    if (i < E) {
        int s = eiA[i], d = eiA[E + i];
        int p = offs[d] + atomicAdd(&cursor[d], 1);
        ssrc[p] = s;
    } else if (i < 2 * E) {
        int j = i - E;
        int s = eiB[j], d = eiB[E + j];
        int g = N + d;
        int p = offs[g] + atomicAdd(&cursor[g], 1);
        ssrc[p] = s;
    }
}

// ---------------- fused: GEMM (both types, bf16 out) + attention scalars + decision MLP ----------------
// LDS reads vectorized to float4 (ds_read_b128): the per-CU LDS pipe is the bottleneck at b32.

template <int M>
__global__ __launch_bounds__(256) void fusedgemm_k(const float* __restrict__ X,
                                                   const float* __restrict__ WA, const float* __restrict__ WB,
                                                   const float* __restrict__ aA0, const float* __restrict__ aA1,
                                                   const float* __restrict__ aB0, const float* __restrict__ aB1,
                                                   const float* __restrict__ dw1, const float* __restrict__ db1,
                                                   const float* __restrict__ dw2, const float* __restrict__ db2,
                                                   __hip_bfloat16* __restrict__ HbA, __hip_bfloat16* __restrict__ HbB,
                                                   float* __restrict__ elA, float* __restrict__ erA,
                                                   float* __restrict__ elB, float* __restrict__ erB,
                                                   float* __restrict__ wdec) {
    constexpr int K = 128;
    constexpr int NB = 16;
    constexpr int G = 256 / M;   // 2 (M=128) or 4 (M=64)
    constexpr int R = NB / G;    // 8 or 4
    __shared__ float xs[NB][K + 4];   // row stride 132 floats = 528B, 16B-aligned
    __shared__ float hid[NB][65];
    __shared__ float lg[16][2];
    int n0 = blockIdx.x * NB;
    int tid = threadIdx.x;
    // float4 staging (X rows are 512B, 16B-aligned)
    for (int idx = tid; idx < NB * (K / 4); idx += 256) {
        int r = idx >> 5, k4 = (idx & 31) << 2;
        *(float4*)&xs[r][k4] = *(const float4*)&X[(size_t)(n0 + r) * K + k4];
    }
    __syncthreads();

    // ---- GEMM both types: float4 xs broadcasts, 16 FMA per b128 pair ----
    const int c = tid % M;
    const int g = tid / M;
    float accA[R], accB[R];
    #pragma unroll
    for (int r = 0; r < R; r++) { accA[r] = 0.f; accB[r] = 0.f; }
    for (int k4 = 0; k4 < K; k4 += 4) {
        float4 xv[R];
        #pragma unroll
        for (int r = 0; r < R; r++) xv[r] = *(float4*)&xs[g * R + r][k4];
        #define GSTEP(comp, kk)                                              \
        {                                                                    \
            float wA = WA[(k4 + kk) * M + c];                                \
            float wB = WB[(k4 + kk) * M + c];                                \
            _Pragma("unroll")                                                \
            for (int r = 0; r < R; r++) {                                    \
                accA[r] = fmaf(xv[r].comp, wA, accA[r]);                     \
                accB[r] = fmaf(xv[r].comp, wB, accB[r]);                     \
            }                                                                \
        }
        GSTEP(x, 0) GSTEP(y, 1) GSTEP(z, 2) GSTEP(w, 3)
        #undef GSTEP
    }

    // ---- decision MLP: float4 xs reads ----
    {
        int dc = tid & 63, dg = tid >> 6;      // 4 groups x 4 rows
        float da[4] = {0.f, 0.f, 0.f, 0.f};
        for (int k4 = 0; k4 < 128; k4 += 4) {
            float4 xr[4];
            #pragma unroll
            for (int r = 0; r < 4; r++) xr[r] = *(float4*)&xs[dg * 4 + r][k4];
            float w0 = dw1[(k4 + 0) * 64 + dc];
            float w1 = dw1[(k4 + 1) * 64 + dc];
            float w2 = dw1[(k4 + 2) * 64 + dc];
            float w3 = dw1[(k4 + 3) * 64 + dc];
            #pragma unroll
            for (int r = 0; r < 4; r++) {
                float s = fmaf(xr[r].x, w0, fmaf(xr[r].y, w1, fmaf(xr[r].z, w2, xr[r].w * w3)));
                da[r] += s;
            }
        }
        float b = db1[dc];
        #pragma unroll
        for (int r = 0; r < 4; r++) hid[dg * 4 + r][dc] = fmaxf(da[r] + b, 0.f);
    }
    __syncthreads();
    if (tid < 32) {
        int node = tid >> 1, o = tid & 1;
        float l = db2[o];
        #pragma unroll 4
        for (int j = 0; j < 64; j++) l += hid[node][j] * dw2[j * 2 + o];
        lg[node][o] = l;
    }
    __syncthreads();
    if (tid < 16) {
        float l0 = lg[tid][0], l1 = lg[tid][1];
        float mm = fmaxf(l0, l1);
        float e0 = __expf(l0 - mm), e1 = __expf(l1 - mm);
        float s = e0 + e1;
        wdec[(size_t)(n0 + tid) * 2 + 0] = e0 / s;
        wdec[(size_t)(n0 + tid) * 2 + 1] = e1 / s;
    }

    // ---- bf16 H stores ----
    #pragma unroll
    for (int r = 0; r < R; r++) {
        HbA[(size_t)(n0 + g * R + r) * M + c] = __float2bfloat16(accA[r]);
        HbB[(size_t)(n0 + g * R + r) * M + c] = __float2bfloat16(accB[r]);
    }

    // ---- attention scalars (reuse xs as scratch) ----
    int row = tid >> 4, lane16 = tid & 15;
    #pragma unroll
    for (int pass = 0; pass < 4; pass++) {
        const float* av = (pass == 0) ? aA0 : (pass == 1) ? aA1 : (pass == 2) ? aB0 : aB1;
        float* dst      = (pass == 0) ? elA : (pass == 1) ? erA : (pass == 2) ? elB : erB;
        float avc = av[c];
        __syncthreads();
        #pragma unroll
        for (int r = 0; r < R; r++)
            xs[g * R + r][c] = ((pass < 2) ? accA[r] : accB[r]) * avc;
        __syncthreads();
        float s = 0.f;
        #pragma unroll
        for (int cc = lane16; cc < M; cc += 16) s += xs[row][cc];
        #pragma unroll
        for (int o = 8; o > 0; o >>= 1) s += __shfl_down(s, o, 16);
        if (lane16 == 0) dst[n0 + row] = s;
    }
}

// ---------------- wave-per-node GAT v4: two-pass softmax, LDS-broadcast pipelined gather ----------------
// N assumed divisible by 4 (N=40000): no early exit, barriers are uniform.

template <int F, bool HEAD>
__global__ __launch_bounds__(256) void gat4_k(const int* __restrict__ offsAll, const int* __restrict__ ssrcAll,
                                              const float* __restrict__ elA, const float* __restrict__ erA,
                                              const float* __restrict__ elB, const float* __restrict__ erB,
                                              const unsigned* __restrict__ HuA, const unsigned* __restrict__ HuB,
                                              const float* __restrict__ wdec,
                                              float* __restrict__ outF,
                                              const float* __restrict__ fc1w, const float* __restrict__ fc1b,
                                              const float* __restrict__ fc2w, const float* __restrict__ fc2b,
                                              float* __restrict__ outP, int N) {
    constexpr int MAXD = 128;                   // Poisson(16): P(deg>128) ~ 1e-80, safe clamp
    __shared__ uint2 se[4][MAXD];               // (src, exBits), wave-private slice
    __shared__ float hs[4][97];                 // head scratch
    const int wid = threadIdx.x >> 6, lane = threadIdx.x & 63;
    const int n = blockIdx.x * 4 + wid;
    const int l5 = lane & 31, sub = lane >> 5;
    float acc0 = 0.f, acc1 = 0.f;

    #pragma unroll
    for (int t = 0; t < 2; t++) {
        const int* offs = offsAll + t * N;
        int beg = offs[n];
        int deg = offs[n + 1] - beg;
        if (deg > MAXD) deg = MAXD;
        const float* el = t ? elB : elA;
        float ern = (t ? erB : erA)[n];
        const unsigned* Hu = t ? HuB : HuA;
        float coef = wdec[(size_t)n * 2 + t];

        __syncthreads();                        // protect previous iteration's se reads
        // pass 1: load src, raw attention value (regs only)
        int sreg[2]; float ereg[2];
        float mx = -1e30f;
        #pragma unroll
        for (int k = 0; k < 2; k++) {
            int j = lane + 64 * k;
            if (j < deg) {
                int s = ssrcAll[beg + j];
                float e = el[s] + ern;
                e = (e > 0.f) ? e : 0.2f * e;
                sreg[k] = s; ereg[k] = e;
                mx = fmaxf(mx, e);
            }
        }
        #pragma unroll
        for (int o = 32; o > 0; o >>= 1) mx = fmaxf(mx, __shfl_xor(mx, o));
        // pass 2: exp, write (src,ex) to LDS, sum
        float sum = 0.f;
        #pragma unroll
        for (int k = 0; k < 2; k++) {
            int j = lane + 64 * k;
            if (j < deg) {
                float ex = __expf(ereg[k] - mx);
                se[wid][j] = make_uint2((unsigned)sreg[k], __float_as_uint(ex));
                sum += ex;
            }
        }
        #pragma unroll
        for (int o = 32; o > 0; o >>= 1) sum += __shfl_xor(sum, o);
        float inv = coef / (sum + 1e-9f);
        __syncthreads();                        // ex visible to all lanes

        // pass 3: pipelined gather, uniform LDS broadcast (no cross-lane shuffles)
        float g0 = 0.f, g1 = 0.f;
        if (F == 128) {
            int j = 0;
            for (; j + 4 <= deg; j += 4) {
                uint2 p0 = se[wid][j], p1 = se[wid][j + 1], p2 = se[wid][j + 2], p3 = se[wid][j + 3];
                unsigned h0 = Hu[(size_t)p0.x * 64 + lane];
                unsigned h1 = Hu[(size_t)p1.x * 64 + lane];
                unsigned h2 = Hu[(size_t)p2.x * 64 + lane];
                unsigned h3 = Hu[(size_t)p3.x * 64 + lane];
                float w0 = __uint_as_float(p0.y), w1 = __uint_as_float(p1.y);
                float w2 = __uint_as_float(p2.y), w3 = __uint_as_float(p3.y);
                g0 = fmaf(w0, __uint_as_float(h0 << 16), g0);
                g1 = fmaf(w0, __uint_as_float(h0 & 0xffff0000u), g1);
                g0 = fmaf(w1, __uint_as_float(h1 << 16), g0);
                g1 = fmaf(w1, __uint_as_float(h1 & 0xffff0000u), g1);
                g0 = fmaf(w2, __uint_as_float(h2 << 16), g0);
                g1 = fmaf(w2, __uint_as_float(h2 & 0xffff0000u), g1);
                g0 = fmaf(w3, __uint_as_float(h3 << 16), g0);
                g1 = fmaf(w3, __uint_as_float(h3 & 0xffff0000u), g1);
            }
            for (; j < deg; j++) {
                uint2 p = se[wid][j];
                unsigned h = Hu[(size_t)p.x * 64 + lane];
                float w = __uint_as_float(p.y);
                g0 = fmaf(w, __uint_as_float(h << 16), g0);
                g1 = fmaf(w, __uint_as_float(h & 0xffff0000u), g1);
            }
        } else {
            // half-wave per edge: sub 0 -> even edges, sub 1 -> odd edges; combined at the very end
            int j = sub;
            for (; j + 7 <= deg; j += 8) {
                uint2 p0 = se[wid][j], p1 = se[wid][j + 2], p2 = se[wid][j + 4], p3 = se[wid][j + 6];
                unsigned h0 = Hu[(size_t)p0.x * 32 + l5];
                unsigned h1 = Hu[(size_t)p1.x * 32 + l5];
                unsigned h2 = Hu[(size_t)p2.x * 32 + l5];
                unsigned h3 = Hu[(size_t)p3.x * 32 + l5];
                float w0 = __uint_as_float(p0.y), w1 = __uint_as_float(p1.y);
                float w2 = __uint_as_float(p2.y), w3 = __uint_as_float(p3.y);
                g0 = fmaf(w0, __uint_as_float(h0 << 16), g0);
                g1 = fmaf(w0, __uint_as_float(h0 & 0xffff0000u), g1);
                g0 = fmaf(w1, __uint_as_float(h1 << 16), g0);
                g1 = fmaf(w1, __uint_as_float(h1 & 0xffff0000u), g1);
                g0 = fmaf(w2, __uint_as_float(h2 << 16), g0);
                g1 = fmaf(w2, __uint_as_float(h2 & 0xffff0000u), g1);
                g0 = fmaf(w3, __uint_as_float(h3 << 16), g0);
                g1 = fmaf(w3, __uint_as_float(h3 & 0xffff0000u), g1);
            }
            for (; j < deg; j += 2) {
                uint2 p = se[wid][j];
                unsigned h = Hu[(size_t)p.x * 32 + l5];
                float w = __uint_as_float(p.y);
                g0 = fmaf(w, __uint_as_float(h << 16), g0);
                g1 = fmaf(w, __uint_as_float(h & 0xffff0000u), g1);
            }
        }
        acc0 = fmaf(inv, g0, acc0);
        acc1 = fmaf(inv, g1, acc1);
    }

    if (F == 64) {                              // combine the two half-wave edge partitions
        acc0 += __shfl_xor(acc0, 32);
        acc1 += __shfl_xor(acc1, 32);
    }

    if (!HEAD) {
        float2 v;
        v.x = fmaxf(acc0, 0.f);
        v.y = fmaxf(acc1, 0.f);
        ((float2*)outF)[(size_t)n * (F / 2) + lane] = v;
    } else {
        // relu -> 64->32 relu -> 2 -> softmax, wave-local
        if (lane < 32) {
            hs[wid][2 * l5 + 0] = fmaxf(acc0, 0.f);
            hs[wid][2 * l5 + 1] = fmaxf(acc1, 0.f);
        }
        if (lane < 32) {
            float h1 = fc1b[lane];
            #pragma unroll 4
            for (int k = 0; k < 64; k++) h1 += hs[wid][k] * fc1w[k * 32 + lane];
            hs[wid][64 + lane] = fmaxf(h1, 0.f);
        }
        if (lane < 2) {
            float l = fc2b[lane];
            #pragma unroll 4
            for (int j = 0; j < 32; j++) l += hs[wid][64 + j] * fc2w[j * 2 + lane];
            float lo = __shfl(l, 0), lhi = __shfl(l, 1);
            if (lane == 0) {
                float mm = fmaxf(lo, lhi);
                float e0 = __expf(lo - mm), e1 = __expf(lhi - mm);
                float s = e0 + e1;
                float2 pr; pr.x = e0 / s; pr.y = e1 / s;
                ((float2*)outP)[n] = pr;
            }
        }
    }
}

// ---------------- launch ----------------

extern "C" void kernel_launch(void* const* d_in, const int* in_sizes, int n_in,
                              void* d_out, int out_size, void* d_ws, size_t ws_size,
                              hipStream_t stream) {
    const float* x     = (const float*)d_in[0];
    const int*   eiA   = (const int*)d_in[1];
    const int*   eiB   = (const int*)d_in[2];
    const float* W1    = (const float*)d_in[3];
    const float* a1    = (const float*)d_in[4];
    const float* d1w1  = (const float*)d_in[5];
    const float* d1b1  = (const float*)d_in[6];
    const float* d1w2  = (const float*)d_in[7];
    const float* d1b2  = (const float*)d_in[8];
    const float* W2    = (const float*)d_in[9];
    const float* a2    = (const float*)d_in[10];
    const float* d2w1  = (const float*)d_in[11];
    const float* d2b1  = (const float*)d_in[12];
    const float* d2w2  = (const float*)d_in[13];
    const float* d2b2  = (const float*)d_in[14];
    const float* fc1w  = (const float*)d_in[15];
    const float* fc1b  = (const float*)d_in[16];
    const float* fc2w  = (const float*)d_in[17];
    const float* fc2b  = (const float*)d_in[18];
    float* out = (float*)d_out;

    const int N = NN, E = EE;

    char* ws = (char*)d_ws;
    size_t off = 0;
    auto alloc = [&](size_t bytes) -> char* {
        char* p = ws + off;
        off = (off + bytes + 255) & ~(size_t)255;
        return p;
    };
    int*   cntAll    = (int*)alloc((size_t)2 * N * sizeof(int));   // adjacent to cursorAll:
    int*   cursorAll = (int*)alloc((size_t)2 * N * sizeof(int));   // one memset covers both
    int*   offsAll   = (int*)alloc(((size_t)2 * N + 1) * sizeof(int));
    int*   ssrcAll   = (int*)alloc((size_t)2 * E * sizeof(int));
    int*   bsum      = (int*)alloc(1024 * sizeof(int));
    float* wdec      = (float*)alloc((size_t)N * 2 * sizeof(float));
    float* elA       = (float*)alloc(N * sizeof(float));
    float* erA       = (float*)alloc(N * sizeof(float));
    float* elB       = (float*)alloc(N * sizeof(float));
    float* erB       = (float*)alloc(N * sizeof(float));
    __hip_bfloat16* HbA = (__hip_bfloat16*)alloc((size_t)N * 128 * sizeof(__hip_bfloat16));
    __hip_bfloat16* HbB = (__hip_bfloat16*)alloc((size_t)N * 128 * sizeof(__hip_bfloat16));
    float* hOut1     = (float*)alloc((size_t)N * 128 * sizeof(float));

    const int twoN = 2 * N, twoE = 2 * E;
    const int nScanBlocks = (twoN + 255) / 256;
    const int nEdgeBlocks = (twoE + 255) / 256;

    // ---- CSR build (both types in one chain) ----
    hipMemsetAsync(cntAll, 0, (size_t)4 * N * sizeof(int), stream);   // cnt + cursor
    hist2_k<<<nEdgeBlocks, 256, 0, stream>>>(eiA + E, eiB + E, E, cntAll, N);
    scan1_k<<<nScanBlocks, 256, 0, stream>>>(cntAll, twoN, offsAll, bsum);
    scan2_k<<<1, 512, 0, stream>>>(bsum, nScanBlocks);
    scan3_k<<<nScanBlocks, 256, 0, stream>>>(offsAll, twoN, bsum, twoE);
    scatter2_k<<<nEdgeBlocks, 256, 0, stream>>>(eiA, eiB, E, offsAll, cursorAll, ssrcAll, N);

    // ---- Layer 1 ----
    fusedgemm_k<128><<<N / 16, 256, 0, stream>>>(x, W1, W1 + 128 * 128,
                                                 a1, a1 + 128, a1 + 2 * 128, a1 + 3 * 128,
                                                 d1w1, d1b1, d1w2, d1b2,
                                                 HbA, HbB, elA, erA, elB, erB, wdec);
    gat4_k<128, false><<<N / 4, 256, 0, stream>>>(offsAll, ssrcAll, elA, erA, elB, erB,
                                                  (const unsigned*)HbA, (const unsigned*)HbB,
                                                  wdec, hOut1,
                                                  nullptr, nullptr, nullptr, nullptr, nullptr, N);

    // ---- Layer 2 (head fused) ----
    fusedgemm_k<64><<<N / 16, 256, 0, stream>>>(hOut1, W2, W2 + 128 * 64,
                                                a2, a2 + 64, a2 + 2 * 64, a2 + 3 * 64,
                                                d2w1, d2b1, d2w2, d2b2,
                                                HbA, HbB, elA, erA, elB, erB, wdec);
    gat4_k<64, true><<<N / 4, 256, 0, stream>>>(offsAll, ssrcAll, elA, erA, elB, erB,
                                                (const unsigned*)HbA, (const unsigned*)HbB,
                                                wdec, nullptr,
                                                fc1w, fc1b, fc2w, fc2b, out, N);
}

// Round 7
// 409.454 us; speedup vs baseline: 1.8808x; 1.1203x over previous
//
#include <hip/hip_runtime.h>
#include <hip/hip_bf16.h>

#define NN   40000
#define EE   640000
#define CAP  64        // ELL slots per (node, edge-type); P(Poisson(16) > 64) ~ 1e-19

// ---------------- ELL build: cursor atomics only (no hist/scan/compact CSR) ----------------

__global__ __launch_bounds__(256) void ellbuild_k(const int* __restrict__ eiA, const int* __restrict__ eiB,
                                                  int E, int* __restrict__ cnt, int* __restrict__ ell, int N) {
    int i = blockIdx.x * 256 + threadIdx.x;
    if (i < E) {
        int s = eiA[i], d = eiA[E + i];
        int c = atomicAdd(&cnt[d], 1);
        if (c < CAP) ell[((size_t)d << 6) + c] = s;
    } else if (i < 2 * E) {
        int j = i - E;
        int s = eiB[j], d = eiB[E + j];
        int g = N + d;
        int c = atomicAdd(&cnt[g], 1);
        if (c < CAP) ell[((size_t)g << 6) + c] = s;
    }
}

// ---------------- fused: GEMM (both types, bf16 out) + attention scalars + decision MLP ----------------

template <int M>
__global__ __launch_bounds__(256) void fusedgemm_k(const float* __restrict__ X,
                                                   const float* __restrict__ WA, const float* __restrict__ WB,
                                                   const float* __restrict__ aA0, const float* __restrict__ aA1,
                                                   const float* __restrict__ aB0, const float* __restrict__ aB1,
                                                   const float* __restrict__ dw1, const float* __restrict__ db1,
                                                   const float* __restrict__ dw2, const float* __restrict__ db2,
                                                   __hip_bfloat16* __restrict__ HbA, __hip_bfloat16* __restrict__ HbB,
                                                   float* __restrict__ elA, float* __restrict__ erA,
                                                   float* __restrict__ elB, float* __restrict__ erB,
                                                   float* __restrict__ wdec) {
    constexpr int K = 128;
    constexpr int NB = 16;
    constexpr int G = 256 / M;   // 2 (M=128) or 4 (M=64)
    constexpr int R = NB / G;    // 8 or 4
    __shared__ float xs[NB][K + 4];   // row stride 132 floats = 528B, 16B-aligned
    __shared__ float hid[NB][65];
    __shared__ float lg[16][2];
    int n0 = blockIdx.x * NB;
    int tid = threadIdx.x;
    for (int idx = tid; idx < NB * (K / 4); idx += 256) {
        int r = idx >> 5, k4 = (idx & 31) << 2;
        *(float4*)&xs[r][k4] = *(const float4*)&X[(size_t)(n0 + r) * K + k4];
    }
    __syncthreads();

    // ---- GEMM both types: float4 xs broadcasts ----
    const int c = tid % M;
    const int g = tid / M;
    float accA[R], accB[R];
    #pragma unroll
    for (int r = 0; r < R; r++) { accA[r] = 0.f; accB[r] = 0.f; }
    for (int k4 = 0; k4 < K; k4 += 4) {
        float4 xv[R];
        #pragma unroll
        for (int r = 0; r < R; r++) xv[r] = *(float4*)&xs[g * R + r][k4];
        #define GSTEP(comp, kk)                                              \
        {                                                                    \
            float wA = WA[(k4 + kk) * M + c];                                \
            float wB = WB[(k4 + kk) * M + c];                                \
            _Pragma("unroll")                                                \
            for (int r = 0; r < R; r++) {                                    \
                accA[r] = fmaf(xv[r].comp, wA, accA[r]);                     \
                accB[r] = fmaf(xv[r].comp, wB, accB[r]);                     \
            }                                                                \
        }
        GSTEP(x, 0) GSTEP(y, 1) GSTEP(z, 2) GSTEP(w, 3)
        #undef GSTEP
    }

    // ---- decision MLP: float4 xs reads ----
    {
        int dc = tid & 63, dg = tid >> 6;      // 4 groups x 4 rows
        float da[4] = {0.f, 0.f, 0.f, 0.f};
        for (int k4 = 0; k4 < 128; k4 += 4) {
            float4 xr[4];
            #pragma unroll
            for (int r = 0; r < 4; r++) xr[r] = *(float4*)&xs[dg * 4 + r][k4];
            float w0 = dw1[(k4 + 0) * 64 + dc];
            float w1 = dw1[(k4 + 1) * 64 + dc];
            float w2 = dw1[(k4 + 2) * 64 + dc];
            float w3 = dw1[(k4 + 3) * 64 + dc];
            #pragma unroll
            for (int r = 0; r < 4; r++) {
                float s = fmaf(xr[r].x, w0, fmaf(xr[r].y, w1, fmaf(xr[r].z, w2, xr[r].w * w3)));
                da[r] += s;
            }
        }
        float b = db1[dc];
        #pragma unroll
        for (int r = 0; r < 4; r++) hid[dg * 4 + r][dc] = fmaxf(da[r] + b, 0.f);
    }
    __syncthreads();
    if (tid < 32) {
        int node = tid >> 1, o = tid & 1;
        float l = db2[o];
        #pragma unroll 4
        for (int j = 0; j < 64; j++) l += hid[node][j] * dw2[j * 2 + o];
        lg[node][o] = l;
    }
    __syncthreads();
    if (tid < 16) {
        float l0 = lg[tid][0], l1 = lg[tid][1];
        float mm = fmaxf(l0, l1);
        float e0 = __expf(l0 - mm), e1 = __expf(l1 - mm);
        float s = e0 + e1;
        wdec[(size_t)(n0 + tid) * 2 + 0] = e0 / s;
        wdec[(size_t)(n0 + tid) * 2 + 1] = e1 / s;
    }

    // ---- bf16 H stores ----
    #pragma unroll
    for (int r = 0; r < R; r++) {
        HbA[(size_t)(n0 + g * R + r) * M + c] = __float2bfloat16(accA[r]);
        HbB[(size_t)(n0 + g * R + r) * M + c] = __float2bfloat16(accB[r]);
    }

    // ---- attention scalars (reuse xs as scratch) ----
    int row = tid >> 4, lane16 = tid & 15;
    #pragma unroll
    for (int pass = 0; pass < 4; pass++) {
        const float* av = (pass == 0) ? aA0 : (pass == 1) ? aA1 : (pass == 2) ? aB0 : aB1;
        float* dst      = (pass == 0) ? elA : (pass == 1) ? erA : (pass == 2) ? elB : erB;
        float avc = av[c];
        __syncthreads();
        #pragma unroll
        for (int r = 0; r < R; r++)
            xs[g * R + r][c] = ((pass < 2) ? accA[r] : accB[r]) * avc;
        __syncthreads();
        float s = 0.f;
        #pragma unroll
        for (int cc = lane16; cc < M; cc += 16) s += xs[row][cc];
        #pragma unroll
        for (int o = 8; o > 0; o >>= 1) s += __shfl_down(s, o, 16);
        if (lane16 == 0) dst[n0 + row] = s;
    }
}

// ---------------- wave-per-node GAT v5: ELL input, single-chunk softmax, BARRIER-FREE ----------------
// deg <= CAP = 64, so one lane per edge; se is wave-private LDS (same-wave RAW needs no barrier).

template <int F, bool HEAD>
__global__ __launch_bounds__(256) void gat5_k(const int* __restrict__ cnt, const int* __restrict__ ell,
                                              const float* __restrict__ elA, const float* __restrict__ erA,
                                              const float* __restrict__ elB, const float* __restrict__ erB,
                                              const unsigned* __restrict__ HuA, const unsigned* __restrict__ HuB,
                                              const float* __restrict__ wdec,
                                              float* __restrict__ outF,
                                              const float* __restrict__ fc1w, const float* __restrict__ fc1b,
                                              const float* __restrict__ fc2w, const float* __restrict__ fc2b,
                                              float* __restrict__ outP, int N) {
    __shared__ uint2 se[4][CAP];                // (src, exBits), wave-private slice
    __shared__ float hs[4][97];                 // head scratch (wave-private)
    const int wid = threadIdx.x >> 6, lane = threadIdx.x & 63;
    const int n = blockIdx.x * 4 + wid;
    const int l5 = lane & 31, sub = lane >> 5;
    float acc0 = 0.f, acc1 = 0.f;

    #pragma unroll
    for (int t = 0; t < 2; t++) {
        int slot = t * N + n;
        int deg = cnt[slot];
        if (deg > CAP) deg = CAP;
        const float* el = t ? elB : elA;
        float ern = (t ? erB : erA)[n];
        const unsigned* Hu = t ? HuB : HuA;
        float coef = wdec[(size_t)n * 2 + t];
        size_t base = (size_t)slot << 6;

        // single-chunk softmax: one edge per lane
        int sv = 0; float ev = -1e30f;
        if (lane < deg) {
            sv = ell[base + lane];
            float e = el[sv] + ern;
            ev = (e > 0.f) ? e : 0.2f * e;
        }
        float mx = ev;
        #pragma unroll
        for (int o = 32; o > 0; o >>= 1) mx = fmaxf(mx, __shfl_xor(mx, o));
        float ex = (lane < deg) ? __expf(ev - mx) : 0.f;
        float sum = ex;
        #pragma unroll
        for (int o = 32; o > 0; o >>= 1) sum += __shfl_xor(sum, o);
        float inv = coef / (sum + 1e-9f);
        se[wid][lane] = make_uint2((unsigned)sv, __float_as_uint(ex));
        // no barrier: wave-private LDS, compiler inserts lgkmcnt wait

        // pipelined gather, uniform LDS broadcast
        float g0 = 0.f, g1 = 0.f;
        if (F == 128) {
            int j = 0;
            for (; j + 4 <= deg; j += 4) {
                uint2 p0 = se[wid][j], p1 = se[wid][j + 1], p2 = se[wid][j + 2], p3 = se[wid][j + 3];
                unsigned h0 = Hu[(size_t)p0.x * 64 + lane];
                unsigned h1 = Hu[(size_t)p1.x * 64 + lane];
                unsigned h2 = Hu[(size_t)p2.x * 64 + lane];
                unsigned h3 = Hu[(size_t)p3.x * 64 + lane];
                float w0 = __uint_as_float(p0.y), w1 = __uint_as_float(p1.y);
                float w2 = __uint_as_float(p2.y), w3 = __uint_as_float(p3.y);
                g0 = fmaf(w0, __uint_as_float(h0 << 16), g0);
                g1 = fmaf(w0, __uint_as_float(h0 & 0xffff0000u), g1);
                g0 = fmaf(w1, __uint_as_float(h1 << 16), g0);
                g1 = fmaf(w1, __uint_as_float(h1 & 0xffff0000u), g1);
                g0 = fmaf(w2, __uint_as_float(h2 << 16), g0);
                g1 = fmaf(w2, __uint_as_float(h2 & 0xffff0000u), g1);
                g0 = fmaf(w3, __uint_as_float(h3 << 16), g0);
                g1 = fmaf(w3, __uint_as_float(h3 & 0xffff0000u), g1);
            }
            for (; j < deg; j++) {
                uint2 p = se[wid][j];
                unsigned h = Hu[(size_t)p.x * 64 + lane];
                float w = __uint_as_float(p.y);
                g0 = fmaf(w, __uint_as_float(h << 16), g0);
                g1 = fmaf(w, __uint_as_float(h & 0xffff0000u), g1);
            }
        } else {
            // half-wave per edge: sub 0 -> even edges, sub 1 -> odd edges
            int j = sub;
            for (; j + 7 <= deg; j += 8) {
                uint2 p0 = se[wid][j], p1 = se[wid][j + 2], p2 = se[wid][j + 4], p3 = se[wid][j + 6];
                unsigned h0 = Hu[(size_t)p0.x * 32 + l5];
                unsigned h1 = Hu[(size_t)p1.x * 32 + l5];
                unsigned h2 = Hu[(size_t)p2.x * 32 + l5];
                unsigned h3 = Hu[(size_t)p3.x * 32 + l5];
                float w0 = __uint_as_float(p0.y), w1 = __uint_as_float(p1.y);
                float w2 = __uint_as_float(p2.y), w3 = __uint_as_float(p3.y);
                g0 = fmaf(w0, __uint_as_float(h0 << 16), g0);
                g1 = fmaf(w0, __uint_as_float(h0 & 0xffff0000u), g1);
                g0 = fmaf(w1, __uint_as_float(h1 << 16), g0);
                g1 = fmaf(w1, __uint_as_float(h1 & 0xffff0000u), g1);
                g0 = fmaf(w2, __uint_as_float(h2 << 16), g0);
                g1 = fmaf(w2, __uint_as_float(h2 & 0xffff0000u), g1);
                g0 = fmaf(w3, __uint_as_float(h3 << 16), g0);
                g1 = fmaf(w3, __uint_as_float(h3 & 0xffff0000u), g1);
            }
            for (; j < deg; j += 2) {
                uint2 p = se[wid][j];
                unsigned h = Hu[(size_t)p.x * 32 + l5];
                float w = __uint_as_float(p.y);
                g0 = fmaf(w, __uint_as_float(h << 16), g0);
                g1 = fmaf(w, __uint_as_float(h & 0xffff0000u), g1);
            }
        }
        acc0 = fmaf(inv, g0, acc0);
        acc1 = fmaf(inv, g1, acc1);
    }

    if (F == 64) {                              // combine the two half-wave edge partitions
        acc0 += __shfl_xor(acc0, 32);
        acc1 += __shfl_xor(acc1, 32);
    }

    if (!HEAD) {
        float2 v;
        v.x = fmaxf(acc0, 0.f);
        v.y = fmaxf(acc1, 0.f);
        ((float2*)outF)[(size_t)n * (F / 2) + lane] = v;
    } else {
        // relu -> 64->32 relu -> 2 -> softmax, wave-local (hs wave-private: no barrier)
        if (lane < 32) {
            hs[wid][2 * l5 + 0] = fmaxf(acc0, 0.f);
            hs[wid][2 * l5 + 1] = fmaxf(acc1, 0.f);
        }
        if (lane < 32) {
            float h1 = fc1b[lane];
            #pragma unroll 4
            for (int k = 0; k < 64; k++) h1 += hs[wid][k] * fc1w[k * 32 + lane];
            hs[wid][64 + lane] = fmaxf(h1, 0.f);
        }
        if (lane < 2) {
            float l = fc2b[lane];
            #pragma unroll 4
            for (int j = 0; j < 32; j++) l += hs[wid][64 + j] * fc2w[j * 2 + lane];
            float lo = __shfl(l, 0), lhi = __shfl(l, 1);
            if (lane == 0) {
                float mm = fmaxf(lo, lhi);
                float e0 = __expf(lo - mm), e1 = __expf(lhi - mm);
                float s = e0 + e1;
                float2 pr; pr.x = e0 / s; pr.y = e1 / s;
                ((float2*)outP)[n] = pr;
            }
        }
    }
}

// ---------------- launch ----------------

extern "C" void kernel_launch(void* const* d_in, const int* in_sizes, int n_in,
                              void* d_out, int out_size, void* d_ws, size_t ws_size,
                              hipStream_t stream) {
    const float* x     = (const float*)d_in[0];
    const int*   eiA   = (const int*)d_in[1];
    const int*   eiB   = (const int*)d_in[2];
    const float* W1    = (const float*)d_in[3];
    const float* a1    = (const float*)d_in[4];
    const float* d1w1  = (const float*)d_in[5];
    const float* d1b1  = (const float*)d_in[6];
    const float* d1w2  = (const float*)d_in[7];
    const float* d1b2  = (const float*)d_in[8];
    const float* W2    = (const float*)d_in[9];
    const float* a2    = (const float*)d_in[10];
    const float* d2w1  = (const float*)d_in[11];
    const float* d2b1  = (const float*)d_in[12];
    const float* d2w2  = (const float*)d_in[13];
    const float* d2b2  = (const float*)d_in[14];
    const float* fc1w  = (const float*)d_in[15];
    const float* fc1b  = (const float*)d_in[16];
    const float* fc2w  = (const float*)d_in[17];
    const float* fc2b  = (const float*)d_in[18];
    float* out = (float*)d_out;

    const int N = NN, E = EE;

    char* ws = (char*)d_ws;
    size_t off = 0;
    auto alloc = [&](size_t bytes) -> char* {
        char* p = ws + off;
        off = (off + bytes + 255) & ~(size_t)255;
        return p;
    };
    int*   cntAll = (int*)alloc((size_t)2 * N * sizeof(int));
    int*   ell    = (int*)alloc((size_t)2 * N * CAP * sizeof(int));
    float* wdec   = (float*)alloc((size_t)N * 2 * sizeof(float));
    float* elA    = (float*)alloc(N * sizeof(float));
    float* erA    = (float*)alloc(N * sizeof(float));
    float* elB    = (float*)alloc(N * sizeof(float));
    float* erB    = (float*)alloc(N * sizeof(float));
    __hip_bfloat16* HbA = (__hip_bfloat16*)alloc((size_t)N * 128 * sizeof(__hip_bfloat16));
    __hip_bfloat16* HbB = (__hip_bfloat16*)alloc((size_t)N * 128 * sizeof(__hip_bfloat16));
    float* hOut1  = (float*)alloc((size_t)N * 128 * sizeof(float));

    const int nEdgeBlocks = (2 * E + 255) / 256;

    // ---- ELL build ----
    hipMemsetAsync(cntAll, 0, (size_t)2 * N * sizeof(int), stream);
    ellbuild_k<<<nEdgeBlocks, 256, 0, stream>>>(eiA, eiB, E, cntAll, ell, N);

    // ---- Layer 1 ----
    fusedgemm_k<128><<<N / 16, 256, 0, stream>>>(x, W1, W1 + 128 * 128,
                                                 a1, a1 + 128, a1 + 2 * 128, a1 + 3 * 128,
                                                 d1w1, d1b1, d1w2, d1b2,
                                                 HbA, HbB, elA, erA, elB, erB, wdec);
    gat5_k<128, false><<<N / 4, 256, 0, stream>>>(cntAll, ell, elA, erA, elB, erB,
                                                  (const unsigned*)HbA, (const unsigned*)HbB,
                                                  wdec, hOut1,
                                                  nullptr, nullptr, nullptr, nullptr, nullptr, N);

    // ---- Layer 2 (head fused) ----
    fusedgemm_k<64><<<N / 16, 256, 0, stream>>>(hOut1, W2, W2 + 128 * 64,
                                                a2, a2 + 64, a2 + 2 * 64, a2 + 3 * 64,
                                                d2w1, d2b1, d2w2, d2b2,
                                                HbA, HbB, elA, erA, elB, erB, wdec);
    gat5_k<64, true><<<N / 4, 256, 0, stream>>>(cntAll, ell, elA, erA, elB, erB,
                                                (const unsigned*)HbA, (const unsigned*)HbB,
                                                wdec, nullptr,
                                                fc1w, fc1b, fc2w, fc2b, out, N);
}

// Round 9
// 361.403 us; speedup vs baseline: 2.1309x; 1.1330x over previous
//
#include <hip/hip_runtime.h>
#include <hip/hip_bf16.h>

#define NN   40000
#define EE   640000
#define CAP  64        // ELL slots per (node, edge-type); P(Poisson(16) > 64) ~ 1e-19

// ---------------- fused: GEMM (both types, bf16 out) + attention scalars + decision MLP
//                  + (layer 1 only) ELL adjacency build hidden under the GEMM ----------------

template <int M, bool BUILD>
__global__ __launch_bounds__(256) void fusedgemm_k(const float* __restrict__ X,
                                                   const float* __restrict__ WA, const float* __restrict__ WB,
                                                   const float* __restrict__ aA0, const float* __restrict__ aA1,
                                                   const float* __restrict__ aB0, const float* __restrict__ aB1,
                                                   const float* __restrict__ dw1, const float* __restrict__ db1,
                                                   const float* __restrict__ dw2, const float* __restrict__ db2,
                                                   __hip_bfloat16* __restrict__ HbA, __hip_bfloat16* __restrict__ HbB,
                                                   float* __restrict__ elA, float* __restrict__ erA,
                                                   float* __restrict__ elB, float* __restrict__ erB,
                                                   float* __restrict__ wdec,
                                                   const int* __restrict__ eiA, const int* __restrict__ eiB,
                                                   int* __restrict__ cnt, int* __restrict__ ell) {
    constexpr int K = 128;
    constexpr int NB = 16;
    constexpr int G = 256 / M;   // 2 (M=128) or 4 (M=64)
    constexpr int R = NB / G;    // 8 or 4
    __shared__ float xs[NB][K + 4];   // row stride 132 floats = 528B, 16B-aligned
    __shared__ float hid[NB][65];
    __shared__ float lg[16][2];
    int n0 = blockIdx.x * NB;
    int tid = threadIdx.x;
    for (int idx = tid; idx < NB * (K / 4); idx += 256) {
        int r = idx >> 5, k4 = (idx & 31) << 2;
        *(float4*)&xs[r][k4] = *(const float4*)&X[(size_t)(n0 + r) * K + k4];
    }
    __syncthreads();

    // ---- ELL build (layer 1): 1 type-A edge + 1 type-B edge per thread.
    // Independent fire-and-forget chains; latency hides under the GEMM FMA stream below.
    if (BUILD) {
        int gid = blockIdx.x * 256 + tid;          // grid is exactly 640000 = E threads
        int sA = eiA[gid], dA = eiA[EE + gid];
        int cA = atomicAdd(&cnt[dA], 1);
        if (cA < CAP) ell[((size_t)dA << 6) + cA] = sA;
        int sB = eiB[gid], dB = NN + eiB[EE + gid];
        int cB = atomicAdd(&cnt[dB], 1);
        if (cB < CAP) ell[((size_t)dB << 6) + cB] = sB;
    }

    // ---- GEMM both types: float4 xs broadcasts ----
    const int c = tid % M;
    const int g = tid / M;
    float accA[R], accB[R];
    #pragma unroll
    for (int r = 0; r < R; r++) { accA[r] = 0.f; accB[r] = 0.f; }
    for (int k4 = 0; k4 < K; k4 += 4) {
        float4 xv[R];
        #pragma unroll
        for (int r = 0; r < R; r++) xv[r] = *(float4*)&xs[g * R + r][k4];
        #define GSTEP(comp, kk)                                              \
        {                                                                    \
            float wA = WA[(k4 + kk) * M + c];                                \
            float wB = WB[(k4 + kk) * M + c];                                \
            _Pragma("unroll")                                                \
            for (int r = 0; r < R; r++) {                                    \
                accA[r] = fmaf(xv[r].comp, wA, accA[r]);                     \
                accB[r] = fmaf(xv[r].comp, wB, accB[r]);                     \
            }                                                                \
        }
        GSTEP(x, 0) GSTEP(y, 1) GSTEP(z, 2) GSTEP(w, 3)
        #undef GSTEP
    }

    // ---- decision MLP: float4 xs reads ----
    {
        int dc = tid & 63, dg = tid >> 6;      // 4 groups x 4 rows
        float da[4] = {0.f, 0.f, 0.f, 0.f};
        for (int k4 = 0; k4 < 128; k4 += 4) {
            float4 xr[4];
            #pragma unroll
            for (int r = 0; r < 4; r++) xr[r] = *(float4*)&xs[dg * 4 + r][k4];
            float w0 = dw1[(k4 + 0) * 64 + dc];
            float w1 = dw1[(k4 + 1) * 64 + dc];
            float w2 = dw1[(k4 + 2) * 64 + dc];
            float w3 = dw1[(k4 + 3) * 64 + dc];
            #pragma unroll
            for (int r = 0; r < 4; r++) {
                float s = fmaf(xr[r].x, w0, fmaf(xr[r].y, w1, fmaf(xr[r].z, w2, xr[r].w * w3)));
                da[r] += s;
            }
        }
        float b = db1[dc];
        #pragma unroll
        for (int r = 0; r < 4; r++) hid[dg * 4 + r][dc] = fmaxf(da[r] + b, 0.f);
    }
    __syncthreads();
    if (tid < 32) {
        int node = tid >> 1, o = tid & 1;
        float l = db2[o];
        #pragma unroll 4
        for (int j = 0; j < 64; j++) l += hid[node][j] * dw2[j * 2 + o];
        lg[node][o] = l;
    }
    __syncthreads();
    if (tid < 16) {
        float l0 = lg[tid][0], l1 = lg[tid][1];
        float mm = fmaxf(l0, l1);
        float e0 = __expf(l0 - mm), e1 = __expf(l1 - mm);
        float s = e0 + e1;
        wdec[(size_t)(n0 + tid) * 2 + 0] = e0 / s;
        wdec[(size_t)(n0 + tid) * 2 + 1] = e1 / s;
    }

    // ---- bf16 H stores ----
    #pragma unroll
    for (int r = 0; r < R; r++) {
        HbA[(size_t)(n0 + g * R + r) * M + c] = __float2bfloat16(accA[r]);
        HbB[(size_t)(n0 + g * R + r) * M + c] = __float2bfloat16(accB[r]);
    }

    // ---- attention scalars (reuse xs as scratch) ----
    int row = tid >> 4, lane16 = tid & 15;
    #pragma unroll
    for (int pass = 0; pass < 4; pass++) {
        const float* av = (pass == 0) ? aA0 : (pass == 1) ? aA1 : (pass == 2) ? aB0 : aB1;
        float* dst      = (pass == 0) ? elA : (pass == 1) ? erA : (pass == 2) ? elB : erB;
        float avc = av[c];
        __syncthreads();
        #pragma unroll
        for (int r = 0; r < R; r++)
            xs[g * R + r][c] = ((pass < 2) ? accA[r] : accB[r]) * avc;
        __syncthreads();
        float s = 0.f;
        #pragma unroll
        for (int cc = lane16; cc < M; cc += 16) s += xs[row][cc];
        #pragma unroll
        for (int o = 8; o > 0; o >>= 1) s += __shfl_down(s, o, 16);
        if (lane16 == 0) dst[n0 + row] = s;
    }
}

// ---------------- wave-per-node GAT v5: ELL input, single-chunk softmax, BARRIER-FREE ----------------
// deg <= CAP = 64, so one lane per edge; se is wave-private LDS (same-wave RAW needs no barrier).

template <int F, bool HEAD>
__global__ __launch_bounds__(256) void gat5_k(const int* __restrict__ cnt, const int* __restrict__ ell,
                                              const float* __restrict__ elA, const float* __restrict__ erA,
                                              const float* __restrict__ elB, const float* __restrict__ erB,
                                              const unsigned* __restrict__ HuA, const unsigned* __restrict__ HuB,
                                              const float* __restrict__ wdec,
                                              float* __restrict__ outF,
                                              const float* __restrict__ fc1w, const float* __restrict__ fc1b,
                                              const float* __restrict__ fc2w, const float* __restrict__ fc2b,
                                              float* __restrict__ outP, int N) {
    __shared__ uint2 se[4][CAP];                // (src, exBits), wave-private slice
    __shared__ float hs[4][97];                 // head scratch (wave-private)
    const int wid = threadIdx.x >> 6, lane = threadIdx.x & 63;
    const int n = blockIdx.x * 4 + wid;
    const int l5 = lane & 31, sub = lane >> 5;
    float acc0 = 0.f, acc1 = 0.f;

    #pragma unroll
    for (int t = 0; t < 2; t++) {
        int slot = t * N + n;
        int deg = cnt[slot];
        if (deg > CAP) deg = CAP;
        const float* el = t ? elB : elA;
        float ern = (t ? erB : erA)[n];
        const unsigned* Hu = t ? HuB : HuA;
        float coef = wdec[(size_t)n * 2 + t];
        size_t base = (size_t)slot << 6;

        // single-chunk softmax: one edge per lane
        int sv = 0; float ev = -1e30f;
        if (lane < deg) {
            sv = ell[base + lane];
            float e = el[sv] + ern;
            ev = (e > 0.f) ? e : 0.2f * e;
        }
        float mx = ev;
        #pragma unroll
        for (int o = 32; o > 0; o >>= 1) mx = fmaxf(mx, __shfl_xor(mx, o));
        float ex = (lane < deg) ? __expf(ev - mx) : 0.f;
        float sum = ex;
        #pragma unroll
        for (int o = 32; o > 0; o >>= 1) sum += __shfl_xor(sum, o);
        float inv = coef / (sum + 1e-9f);
        se[wid][lane] = make_uint2((unsigned)sv, __float_as_uint(ex));
        // no barrier: wave-private LDS, compiler inserts lgkmcnt wait

        // pipelined gather, uniform LDS broadcast
        float g0 = 0.f, g1 = 0.f;
        if (F == 128) {
            int j = 0;
            for (; j + 4 <= deg; j += 4) {
                uint2 p0 = se[wid][j], p1 = se[wid][j + 1], p2 = se[wid][j + 2], p3 = se[wid][j + 3];
                unsigned h0 = Hu[(size_t)p0.x * 64 + lane];
                unsigned h1 = Hu[(size_t)p1.x * 64 + lane];
                unsigned h2 = Hu[(size_t)p2.x * 64 + lane];
                unsigned h3 = Hu[(size_t)p3.x * 64 + lane];
                float w0 = __uint_as_float(p0.y), w1 = __uint_as_float(p1.y);
                float w2 = __uint_as_float(p2.y), w3 = __uint_as_float(p3.y);
                g0 = fmaf(w0, __uint_as_float(h0 << 16), g0);
                g1 = fmaf(w0, __uint_as_float(h0 & 0xffff0000u), g1);
                g0 = fmaf(w1, __uint_as_float(h1 << 16), g0);
                g1 = fmaf(w1, __uint_as_float(h1 & 0xffff0000u), g1);
                g0 = fmaf(w2, __uint_as_float(h2 << 16), g0);
                g1 = fmaf(w2, __uint_as_float(h2 & 0xffff0000u), g1);
                g0 = fmaf(w3, __uint_as_float(h3 << 16), g0);
                g1 = fmaf(w3, __uint_as_float(h3 & 0xffff0000u), g1);
            }
            for (; j < deg; j++) {
                uint2 p = se[wid][j];
                unsigned h = Hu[(size_t)p.x * 64 + lane];
                float w = __uint_as_float(p.y);
                g0 = fmaf(w, __uint_as_float(h << 16), g0);
                g1 = fmaf(w, __uint_as_float(h & 0xffff0000u), g1);
            }
        } else {
            // half-wave per edge: sub 0 -> even edges, sub 1 -> odd edges
            int j = sub;
            for (; j + 7 <= deg; j += 8) {
                uint2 p0 = se[wid][j], p1 = se[wid][j + 2], p2 = se[wid][j + 4], p3 = se[wid][j + 6];
                unsigned h0 = Hu[(size_t)p0.x * 32 + l5];
                unsigned h1 = Hu[(size_t)p1.x * 32 + l5];
                unsigned h2 = Hu[(size_t)p2.x * 32 + l5];
                unsigned h3 = Hu[(size_t)p3.x * 32 + l5];
                float w0 = __uint_as_float(p0.y), w1 = __uint_as_float(p1.y);
                float w2 = __uint_as_float(p2.y), w3 = __uint_as_float(p3.y);
                g0 = fmaf(w0, __uint_as_float(h0 << 16), g0);
                g1 = fmaf(w0, __uint_as_float(h0 & 0xffff0000u), g1);
                g0 = fmaf(w1, __uint_as_float(h1 << 16), g0);
                g1 = fmaf(w1, __uint_as_float(h1 & 0xffff0000u), g1);
                g0 = fmaf(w2, __uint_as_float(h2 << 16), g0);
                g1 = fmaf(w2, __uint_as_float(h2 & 0xffff0000u), g1);
                g0 = fmaf(w3, __uint_as_float(h3 << 16), g0);
                g1 = fmaf(w3, __uint_as_float(h3 & 0xffff0000u), g1);
            }
            for (; j < deg; j += 2) {
                uint2 p = se[wid][j];
                unsigned h = Hu[(size_t)p.x * 32 + l5];
                float w = __uint_as_float(p.y);
                g0 = fmaf(w, __uint_as_float(h << 16), g0);
                g1 = fmaf(w, __uint_as_float(h & 0xffff0000u), g1);
            }
        }
        acc0 = fmaf(inv, g0, acc0);
        acc1 = fmaf(inv, g1, acc1);
    }

    if (F == 64) {                              // combine the two half-wave edge partitions
        acc0 += __shfl_xor(acc0, 32);
        acc1 += __shfl_xor(acc1, 32);
    }

    if (!HEAD) {
        float2 v;
        v.x = fmaxf(acc0, 0.f);
        v.y = fmaxf(acc1, 0.f);
        ((float2*)outF)[(size_t)n * (F / 2) + lane] = v;
    } else {
        // relu -> 64->32 relu -> 2 -> softmax, wave-local (hs wave-private: no barrier)
        if (lane < 32) {
            hs[wid][2 * l5 + 0] = fmaxf(acc0, 0.f);
            hs[wid][2 * l5 + 1] = fmaxf(acc1, 0.f);
        }
        if (lane < 32) {
            float h1 = fc1b[lane];
            #pragma unroll 4
            for (int k = 0; k < 64; k++) h1 += hs[wid][k] * fc1w[k * 32 + lane];
            hs[wid][64 + lane] = fmaxf(h1, 0.f);
        }
        if (lane < 2) {
            float l = fc2b[lane];
            #pragma unroll 4
            for (int j = 0; j < 32; j++) l += hs[wid][64 + j] * fc2w[j * 2 + lane];
            float lo = __shfl(l, 0), lhi = __shfl(l, 1);
            if (lane == 0) {
                float mm = fmaxf(lo, lhi);
                float e0 = __expf(lo - mm), e1 = __expf(lhi - mm);
                float s = e0 + e1;
                float2 pr; pr.x = e0 / s; pr.y = e1 / s;
                ((float2*)outP)[n] = pr;
            }
        }
    }
}

// ---------------- launch ----------------

extern "C" void kernel_launch(void* const* d_in, const int* in_sizes, int n_in,
                              void* d_out, int out_size, void* d_ws, size_t ws_size,
                              hipStream_t stream) {
    const float* x     = (const float*)d_in[0];
    const int*   eiA   = (const int*)d_in[1];
    const int*   eiB   = (const int*)d_in[2];
    const float* W1    = (const float*)d_in[3];
    const float* a1    = (const float*)d_in[4];
    const float* d1w1  = (const float*)d_in[5];
    const float* d1b1  = (const float*)d_in[6];
    const float* d1w2  = (const float*)d_in[7];
    const float* d1b2  = (const float*)d_in[8];
    const float* W2    = (const float*)d_in[9];
    const float* a2    = (const float*)d_in[10];
    const float* d2w1  = (const float*)d_in[11];
    const float* d2b1  = (const float*)d_in[12];
    const float* d2w2  = (const float*)d_in[13];
    const float* d2b2  = (const float*)d_in[14];
    const float* fc1w  = (const float*)d_in[15];
    const float* fc1b  = (const float*)d_in[16];
    const float* fc2w  = (const float*)d_in[17];
    const float* fc2b  = (const float*)d_in[18];
    float* out = (float*)d_out;

    const int N = NN;

    char* ws = (char*)d_ws;
    size_t off = 0;
    auto alloc = [&](size_t bytes) -> char* {
        char* p = ws + off;
        off = (off + bytes + 255) & ~(size_t)255;
        return p;
    };
    int*   cntAll = (int*)alloc((size_t)2 * N * sizeof(int));
    int*   ell    = (int*)alloc((size_t)2 * N * CAP * sizeof(int));
    float* wdec   = (float*)alloc((size_t)N * 2 * sizeof(float));
    float* elA    = (float*)alloc(N * sizeof(float));
    float* erA    = (float*)alloc(N * sizeof(float));
    float* elB    = (float*)alloc(N * sizeof(float));
    float* erB    = (float*)alloc(N * sizeof(float));
    __hip_bfloat16* HbA = (__hip_bfloat16*)alloc((size_t)N * 128 * sizeof(__hip_bfloat16));
    __hip_bfloat16* HbB = (__hip_bfloat16*)alloc((size_t)N * 128 * sizeof(__hip_bfloat16));
    float* hOut1  = (float*)alloc((size_t)N * 128 * sizeof(float));

    // ---- cnt zero (ELL build itself is fused into the layer-1 GEMM) ----
    hipMemsetAsync(cntAll, 0, (size_t)2 * N * sizeof(int), stream);

    // ---- Layer 1 (+ ELL build hidden under the GEMM) ----
    fusedgemm_k<128, true><<<N / 16, 256, 0, stream>>>(x, W1, W1 + 128 * 128,
                                                       a1, a1 + 128, a1 + 2 * 128, a1 + 3 * 128,
                                                       d1w1, d1b1, d1w2, d1b2,
                                                       HbA, HbB, elA, erA, elB, erB, wdec,
                                                       eiA, eiB, cntAll, ell);
    gat5_k<128, false><<<N / 4, 256, 0, stream>>>(cntAll, ell, elA, erA, elB, erB,
                                                  (const unsigned*)HbA, (const unsigned*)HbB,
                                                  wdec, hOut1,
                                                  nullptr, nullptr, nullptr, nullptr, nullptr, N);

    // ---- Layer 2 (head fused) ----
    fusedgemm_k<64, false><<<N / 16, 256, 0, stream>>>(hOut1, W2, W2 + 128 * 64,
                                                       a2, a2 + 64, a2 + 2 * 64, a2 + 3 * 64,
                                                       d2w1, d2b1, d2w2, d2b2,
                                                       HbA, HbB, elA, erA, elB, erB, wdec,
                                                       nullptr, nullptr, nullptr, nullptr);
    gat5_k<64, true><<<N / 4, 256, 0, stream>>>(cntAll, ell, elA, erA, elB, erB,
                                                (const unsigned*)HbA, (const unsigned*)HbB,
                                                wdec, nullptr,
                                                fc1w, fc1b, fc2w, fc2b, out, N);
}